// Round 6
// baseline (648.893 us; speedup 1.0000x reference)
//
#include <hip/hip_runtime.h>
#include <hip/hip_bf16.h>

typedef unsigned int uint;
typedef unsigned short ushort;
typedef __attribute__((ext_vector_type(8))) short bf16x8;
typedef __attribute__((ext_vector_type(4))) float f32x4;

#define Tn 128
#define Bn 16
#define HH 128
#define G3 384
#define DIN 1024
#define PAD 136   // ushort row stride (272 B = 16*17, keeps 16B alignment, breaks pow2 banks)

#if __has_builtin(__builtin_amdgcn_cvt_pk_bf16_f32)
__device__ __forceinline__ uint pack2(float a, float b){
    auto v = __builtin_amdgcn_cvt_pk_bf16_f32(a, b);   // lo = a, hi = b, RNE
    union { decltype(v) v2; uint u; } c; c.v2 = v;
    return c.u;
}
#else
__device__ __forceinline__ ushort f2bf_(float f){
    union{float f; uint u;} c; c.f = f;
    uint u = c.u + 0x7fffu + ((c.u >> 16) & 1u);   // RNE to bf16
    return (ushort)(u >> 16);
}
__device__ __forceinline__ uint pack2(float a, float b){
    return ((uint)f2bf_(b) << 16) | (uint)f2bf_(a);
}
#endif
__device__ __forceinline__ ushort f2bf(float f){ return (ushort)(pack2(f, f) & 0xffffu); }

__device__ __forceinline__ float sigm(float x){ return 1.f/(1.f + __expf(-x)); }
__device__ __forceinline__ float tanhx(float x){
    float t = __expf(-2.f*fabsf(x));
    float r = (1.f - t)/(1.f + t);
    return x >= 0.f ? r : -r;
}
__device__ __forceinline__ float lo16u(uint u){ union{uint i; float f;} c; c.i = u << 16; return c.f; }
__device__ __forceinline__ float hi16u(uint u){ union{uint i; float f;} c; c.i = u & 0xffff0000u; return c.f; }

// ============ fused emb + Gi + WoE, all MFMA. 128 blocks x 512 threads, 16 rows each.
// Gi written bf16, P-permuted, [pos][b][g], with bih (+bhh for r,z gates) folded in.
__global__ __launch_bounds__(512) void k_embgi(
    const float* __restrict__ x,    const float* __restrict__ Wemb,
    const float* __restrict__ Wiha, const float* __restrict__ biha, const float* __restrict__ bhha,
    const float* __restrict__ Wihb, const float* __restrict__ bihb, const float* __restrict__ bhhb,
    const float* __restrict__ Wo,
    ushort* __restrict__ gia, ushort* __restrict__ gib, ushort* __restrict__ woE)
{
    __shared__ __align__(16) ushort LX[16*PAD];    // x chunk (16 rows x 128 k)
    __shared__ __align__(16) ushort LW[128*PAD];   // weight chunk (128 rows x 128 k)
    __shared__ __align__(16) ushort LE[16*PAD];    // emb bf16 [m][e]
    int tid = threadIdx.x;
    int lane = tid & 63, wave = tid >> 6;
    int quad = lane >> 4, n = lane & 15;
    int R0 = blockIdx.x * 16;
    int xr = tid >> 5, xc = (tid & 31) * 4;     // x staging
    int wr_ = tid >> 2, wc = (tid & 3) * 32;    // W staging

    f32x4 acc = {0.f,0.f,0.f,0.f};
    // ---- Phase 1: emb = x @ Wemb^T over 8 K-chunks
    for (int kc = 0; kc < 8; ++kc){
        __syncthreads();
        {
            float4 v = *(const float4*)(x + (size_t)(R0 + xr)*DIN + kc*128 + xc);
            *(uint2*)&LX[xr*PAD + xc] = (uint2){pack2(v.x,v.y), pack2(v.z,v.w)};
            const float4* sw = (const float4*)(Wemb + (size_t)wr_*DIN + kc*128 + wc);
            float4 g0=sw[0],g1=sw[1],g2=sw[2],g3=sw[3],g4=sw[4],g5=sw[5],g6=sw[6],g7=sw[7];
            uint4* dB = (uint4*)&LW[wr_*PAD + wc];
            dB[0] = (uint4){pack2(g0.x,g0.y),pack2(g0.z,g0.w),pack2(g1.x,g1.y),pack2(g1.z,g1.w)};
            dB[1] = (uint4){pack2(g2.x,g2.y),pack2(g2.z,g2.w),pack2(g3.x,g3.y),pack2(g3.z,g3.w)};
            dB[2] = (uint4){pack2(g4.x,g4.y),pack2(g4.z,g4.w),pack2(g5.x,g5.y),pack2(g5.z,g5.w)};
            dB[3] = (uint4){pack2(g6.x,g6.y),pack2(g6.z,g6.w),pack2(g7.x,g7.y),pack2(g7.z,g7.w)};
        }
        __syncthreads();
#pragma unroll
        for (int kb = 0; kb < 4; ++kb){
            bf16x8 a = *(const bf16x8*)&LX[n*PAD + kb*32 + quad*8];
            bf16x8 b = *(const bf16x8*)&LW[(wave*16 + n)*PAD + kb*32 + quad*8];
            acc = __builtin_amdgcn_mfma_f32_16x16x32_bf16(a, b, acc, 0,0,0);
        }
    }
    {   // epilogue: emb bf16 -> LE; WoE -> global
        int e = wave*16 + n;
        float wo = Wo[e];
#pragma unroll
        for (int l = 0; l < 4; ++l){
            int m = quad*4 + l;
            LE[m*PAD + e] = f2bf(acc[l]);
            int row = R0 + m, b_ = row >> 7, pos = row & 127;
            woE[((size_t)(pos*Bn + b_))*HH + e] = f2bf(wo * acc[l]);
        }
    }
    // ---- Phase 2: Gi = emb @ Wih^T + (bih [+bhh]), 6 chunks of 128 gate rows
    for (int nc = 0; nc < 6; ++nc){
        const float* Wsrc = (nc < 3) ? Wiha : Wihb;
        int gband = (nc < 3) ? nc : nc - 3;
        __syncthreads();   // LE visible; previous chunk's LW reads done
        {
            const float4* sw = (const float4*)(Wsrc + (size_t)(gband*128 + wr_)*HH + wc);
            float4 g0=sw[0],g1=sw[1],g2=sw[2],g3=sw[3],g4=sw[4],g5=sw[5],g6=sw[6],g7=sw[7];
            uint4* dB = (uint4*)&LW[wr_*PAD + wc];
            dB[0] = (uint4){pack2(g0.x,g0.y),pack2(g0.z,g0.w),pack2(g1.x,g1.y),pack2(g1.z,g1.w)};
            dB[1] = (uint4){pack2(g2.x,g2.y),pack2(g2.z,g2.w),pack2(g3.x,g3.y),pack2(g3.z,g3.w)};
            dB[2] = (uint4){pack2(g4.x,g4.y),pack2(g4.z,g4.w),pack2(g5.x,g5.y),pack2(g5.z,g5.w)};
            dB[3] = (uint4){pack2(g6.x,g6.y),pack2(g6.z,g6.w),pack2(g7.x,g7.y),pack2(g7.z,g7.w)};
        }
        __syncthreads();
        f32x4 gc = {0.f,0.f,0.f,0.f};
#pragma unroll
        for (int kb = 0; kb < 4; ++kb){
            bf16x8 a = *(const bf16x8*)&LE[n*PAD + kb*32 + quad*8];
            bf16x8 b = *(const bf16x8*)&LW[(wave*16 + n)*PAD + kb*32 + quad*8];
            gc = __builtin_amdgcn_mfma_f32_16x16x32_bf16(a, b, gc, 0,0,0);
        }
        int j = wave*16 + n;             // gate row within band
        int g = gband*128 + j;           // gate row in [0,384)
        const float* bi = (nc < 3) ? biha : bihb;
        const float* bh = (nc < 3) ? bhha : bhhb;
        float bias = bi[g] + ((gband < 2) ? bh[g] : 0.f);   // fold bhh for r,z only
        ushort* dst = (nc < 3) ? gia : gib;
        int P = (3*wave + gband)*16 + n;
#pragma unroll
        for (int l = 0; l < 4; ++l){
            int row = R0 + quad*4 + l, b_ = row >> 7, pos = row & 127;
            dst[((size_t)(pos*Bn + b_))*G3 + P] = f2bf(gc[l] + bias);
        }
    }
}

// ============ Merged GRU-a + GRU-b recurrence for one i. 1024 threads:
// waves 0-7 = GRU-a (emits s), waves 8-15 = GRU-b (emits q). One barrier/step,
// shared between halves; s/q buffered in LDS, flushed once at the end.
__global__ __launch_bounds__(1024) void k_gru(
    const float* __restrict__ WhhA, const float* __restrict__ bhhA,
    const float* __restrict__ Wa,   const float* __restrict__ ba,
    const float* __restrict__ WhhB, const float* __restrict__ bhhB,
    const float* __restrict__ Wb,   const float* __restrict__ bb,
    const ushort* __restrict__ GiA, const ushort* __restrict__ GiB,
    const ushort* __restrict__ WoE,
    float* __restrict__ sW, float* __restrict__ qW)
{
    __shared__ __align__(16) ushort HF[2][2][2048];   // [gt][dbuf] h in B-frag order
    __shared__ float RED[2][2][128];                  // [gt][dbuf] partials
    __shared__ __align__(16) float SQ[2][16][128];    // [gt][chain][k] s / q
    int tid = threadIdx.x;
    int wave = tid >> 6, lane = tid & 63;
    int gt = wave >> 3, u = wave & 7;
    int quad = lane >> 4, n = lane & 15;
    int i = Tn - 1 - blockIdx.x;
    int jb = u*16 + quad*4;

    const float* Whh = gt ? WhhB : WhhA;
    const float* bhh = gt ? bhhB : bhhA;
    const float* W3  = gt ? Wb   : WhhA;   // gt0: valid dummy (acc3 unused)
    const ushort* Gi = gt ? GiB  : GiA;
    float sc3 = gt ? 0.5f : 1.0f;          // fold 0.5 into Wb fragments

    bf16x8 afr[4][4];
#pragma unroll
    for (int g = 0; g < 4; ++g){
        const float* src = (g < 3) ? (Whh + (size_t)(g*HH + u*16 + n)*HH)
                                   : (W3  + (size_t)(u*16 + n)*HH);
#pragma unroll
        for (int kb = 0; kb < 4; ++kb){
            const float* p = src + kb*32 + quad*8;
            float4 a = *(const float4*)p, b2 = *(const float4*)(p+4);
            float s = (g == 3) ? sc3 : 1.0f;
            union { uint4 q; bf16x8 v; } cv;
            cv.q.x = pack2(s*a.x,  s*a.y);  cv.q.y = pack2(s*a.z,  s*a.w);
            cv.q.z = pack2(s*b2.x, s*b2.y); cv.q.w = pack2(s*b2.z, s*b2.w);
            afr[g][kb] = cv.v;
        }
    }
    float bh2[4], wsc4[4];
#pragma unroll
    for (int l = 0; l < 4; ++l){
        bh2[l]  = bhh[2*HH + jb + l];
        wsc4[l] = gt ? bb[jb + l] : 0.5f*Wa[jb + l];   // gt1: beta offset; gt0: 0.5*Wa
    }
    float bav = gt ? 0.f : ba[0];
    float h4[4] = {0.f,0.f,0.f,0.f};
    {
        int t = tid & 511;
        if (t < 256) ((uint4*)HF[gt][1])[t] = (uint4){0,0,0,0};
    }
    const ushort* gp = Gi + ((size_t)(i*Bn + n))*G3 + u*48 + quad*4;
    uint2 pg0 = *(const uint2*)(gp);
    uint2 pg1 = *(const uint2*)(gp + 16);
    uint2 pg2 = *(const uint2*)(gp + 32);
    uint2 pwo = {0,0};
    __syncthreads();

    for (int k = 0; k <= i; ++k){
        int pos = i - k;
        // finish previous step's scalar into LDS (pipelined; no global store)
        if (lane < 16 && u == 0){
            if (!gt && k > 0){
                const float* R = RED[0][(k+1)&1];
                SQ[0][lane][k-1] = R[lane]+R[16+lane]+R[32+lane]+R[48+lane]
                                 + R[64+lane]+R[80+lane]+R[96+lane]+R[112+lane] + bav;
            }
            if (gt && k > 1){
                const float* R = RED[1][(k+1)&1];
                SQ[1][lane][k-2] = R[lane]+R[16+lane]+R[32+lane]+R[48+lane]
                                 + R[64+lane]+R[80+lane]+R[96+lane]+R[112+lane];
            }
        }
        uint2 g0 = pg0, g1 = pg1, g2 = pg2, wo = pwo;
        int pnext = (pos > 0) ? pos - 1 : 0;
        const ushort* gp2 = Gi + ((size_t)(pnext*Bn + n))*G3 + u*48 + quad*4;
        pg0 = *(const uint2*)(gp2);
        pg1 = *(const uint2*)(gp2 + 16);
        pg2 = *(const uint2*)(gp2 + 32);
        if (gt) pwo = *(const uint2*)(WoE + (size_t)(pos*Bn + n)*HH + jb);

        const ushort* HR = HF[gt][(k+1)&1];
        f32x4 a0={0.f,0.f,0.f,0.f}, a1=a0, a2=a0, a3=a0;
#pragma unroll
        for (int kb = 0; kb < 4; ++kb){
            bf16x8 bfr = *(const bf16x8*)&HR[(64*kb + lane)*8];
            a0 = __builtin_amdgcn_mfma_f32_16x16x32_bf16(afr[0][kb], bfr, a0, 0,0,0);
            a1 = __builtin_amdgcn_mfma_f32_16x16x32_bf16(afr[1][kb], bfr, a1, 0,0,0);
            a2 = __builtin_amdgcn_mfma_f32_16x16x32_bf16(afr[2][kb], bfr, a2, 0,0,0);
            a3 = __builtin_amdgcn_mfma_f32_16x16x32_bf16(afr[3][kb], bfr, a3, 0,0,0);
        }

        float part = 0.f;
        if (gt){   // q_{k-1}: 0.5*Wb h_{k-1} (in a3) with WoE prefetched last step
            float wof[4] = {lo16u(wo.x), hi16u(wo.x), lo16u(wo.y), hi16u(wo.y)};
#pragma unroll
            for (int l = 0; l < 4; ++l)
                part = fmaf(wof[l], tanhx(a3[l] + wsc4[l]), part);
        }
        float gi0[4] = {lo16u(g0.x), hi16u(g0.x), lo16u(g0.y), hi16u(g0.y)};
        float gi1[4] = {lo16u(g1.x), hi16u(g1.x), lo16u(g1.y), hi16u(g1.y)};
        float gi2[4] = {lo16u(g2.x), hi16u(g2.x), lo16u(g2.y), hi16u(g2.y)};
#pragma unroll
        for (int l = 0; l < 4; ++l){
            float r = sigm(gi0[l] + a0[l]);                 // bhh_r folded into Gi
            float z = sigm(gi1[l] + a1[l]);                 // bhh_z folded into Gi
            float nn = tanhx(gi2[l] + r*(a2[l] + bh2[l]));
            h4[l] = (1.f - z)*nn + z*h4[l];
        }
        if (!gt) part = wsc4[0]*h4[0] + wsc4[1]*h4[1] + wsc4[2]*h4[2] + wsc4[3]*h4[3];

        {
            ushort* HW = HF[gt][k&1];
            *(uint2*)&HW[((jb>>3)*16 + n)*8 + (jb&4)] =
                (uint2){pack2(h4[0],h4[1]), pack2(h4[2],h4[3])};
        }
        part += __shfl_xor(part, 16);
        part += __shfl_xor(part, 32);
        if (lane < 16) RED[gt][k&1][u*16 + n] = part;
        __syncthreads();
    }

    // ---- tail
    if (lane < 16 && u == 0){
        const float* R = RED[gt][i&1];
        float sum = R[lane]+R[16+lane]+R[32+lane]+R[48+lane]
                  + R[64+lane]+R[80+lane]+R[96+lane]+R[112+lane];
        if (!gt)        SQ[0][lane][i] = sum + bav;
        else if (i > 0) SQ[1][lane][i-1] = sum;
    }
    if (gt){   // q_i from final h (HF[i&1]) with WoE[pos=0] (in pwo)
        const ushort* HR = HF[1][i&1];
        f32x4 a3 = {0.f,0.f,0.f,0.f};
#pragma unroll
        for (int kb = 0; kb < 4; ++kb){
            bf16x8 bfr = *(const bf16x8*)&HR[(64*kb + lane)*8];
            a3 = __builtin_amdgcn_mfma_f32_16x16x32_bf16(afr[3][kb], bfr, a3, 0,0,0);
        }
        float wof[4] = {lo16u(pwo.x), hi16u(pwo.x), lo16u(pwo.y), hi16u(pwo.y)};
        float part = 0.f;
#pragma unroll
        for (int l = 0; l < 4; ++l)
            part = fmaf(wof[l], tanhx(a3[l] + wsc4[l]), part);
        part += __shfl_xor(part, 16);
        part += __shfl_xor(part, 32);
        if (lane < 16) RED[1][(i+1)&1][u*16 + n] = part;
    }
    __syncthreads();
    if (gt && lane < 16 && u == 0){
        const float* R = RED[1][(i+1)&1];
        SQ[1][lane][i] = R[lane]+R[16+lane]+R[32+lane]+R[48+lane]
                       + R[64+lane]+R[80+lane]+R[96+lane]+R[112+lane];
    }
    __syncthreads();
    {   // flush SQ -> global, coalesced float4
        int t = tid & 511;
        int cn = t >> 5, k4 = (t & 31) * 4;
        float4 v = *(const float4*)&SQ[gt][cn][k4];
        float* dst = gt ? qW : sW;
        *(float4*)&dst[((size_t)(cn*Tn + i))*Tn + k4] = v;
    }
}

// ============ softmax(s) . q per row; one wave per (b,i)
__global__ __launch_bounds__(256) void k_out(const float* __restrict__ sW,
                                             const float* __restrict__ qW,
                                             const float* __restrict__ bo,
                                             float* __restrict__ out){
    int tid = threadIdx.x, lane = tid & 63, w = tid >> 6;
    int r = blockIdx.x*4 + w;
    int i = r & (Tn-1);
    const float* s = sW + (size_t)r*Tn;
    const float* q = qW + (size_t)r*Tn;
    float s0 = (lane     <= i) ? s[lane]      : -1e30f;
    float s1 = (64+lane  <= i) ? s[64+lane]   : -1e30f;
    float m = fmaxf(s0, s1);
#pragma unroll
    for (int off = 32; off; off >>= 1) m = fmaxf(m, __shfl_xor(m, off));
    float e0 = __expf(s0 - m), e1 = __expf(s1 - m);
    float q0 = (lane    <= i) ? q[lane]    : 0.f;
    float q1 = (64+lane <= i) ? q[64+lane] : 0.f;
    float num = e0*q0 + e1*q1, den = e0 + e1;
#pragma unroll
    for (int off = 32; off; off >>= 1){
        num += __shfl_xor(num, off);
        den += __shfl_xor(den, off);
    }
    if (lane == 0) out[r] = num/den + bo[0];
}

extern "C" void kernel_launch(void* const* d_in, const int* in_sizes, int n_in,
                              void* d_out, int out_size, void* d_ws, size_t ws_size,
                              hipStream_t stream) {
    const float* x     = (const float*)d_in[0];
    const float* Wemb  = (const float*)d_in[1];
    const float* Wih_a = (const float*)d_in[2];
    const float* Whh_a = (const float*)d_in[3];
    const float* bih_a = (const float*)d_in[4];
    const float* bhh_a = (const float*)d_in[5];
    const float* Wa    = (const float*)d_in[6];
    const float* ba    = (const float*)d_in[7];
    const float* Wih_b = (const float*)d_in[8];
    const float* Whh_b = (const float*)d_in[9];
    const float* bih_b = (const float*)d_in[10];
    const float* bhh_b = (const float*)d_in[11];
    const float* Wb    = (const float*)d_in[12];
    const float* bb    = (const float*)d_in[13];
    const float* Wo    = (const float*)d_in[14];
    const float* bo    = (const float*)d_in[15];

    const int NR = Bn*Tn;                            // 2048 rows
    ushort* giA = (ushort*)d_ws;                     // [pos][b][384] bf16, P-permuted
    ushort* giB = giA + (size_t)NR*G3;
    ushort* woE = giB + (size_t)NR*G3;               // [pos][b][128] bf16
    float*  sW  = (float*)(woE + (size_t)NR*HH);     // [b][i][k] fp32
    float*  qW  = sW + (size_t)NR*Tn;

    k_embgi<<<dim3(128), 512, 0, stream>>>(x, Wemb,
                                           Wih_a, bih_a, bhh_a,
                                           Wih_b, bih_b, bhh_b, Wo,
                                           giA, giB, woE);
    k_gru<<<dim3(128), 1024, 0, stream>>>(Whh_a, bhh_a, Wa, ba,
                                          Whh_b, bhh_b, Wb, bb,
                                          giA, giB, woE, sW, qW);
    k_out<<<dim3(NR/4), 256, 0, stream>>>(sW, qW, bo, (float*)d_out);
}

// Round 7
// 343.222 us; speedup vs baseline: 1.8906x; 1.8906x over previous
//
#include <hip/hip_runtime.h>
#include <hip/hip_bf16.h>

typedef unsigned int uint;
typedef unsigned short ushort;
typedef __attribute__((ext_vector_type(8))) short bf16x8;
typedef __attribute__((ext_vector_type(4))) float f32x4;

#define Tn 128
#define Bn 16
#define HH 128
#define G3 384
#define DIN 1024
#define PAD 136   // ushort row stride (272 B, 16B-aligned, breaks pow2 banks)

#if __has_builtin(__builtin_amdgcn_cvt_pk_bf16_f32)
__device__ __forceinline__ uint pack2(float a, float b){
    auto v = __builtin_amdgcn_cvt_pk_bf16_f32(a, b);   // lo = a, hi = b, RNE
    union { decltype(v) v2; uint u; } c; c.v2 = v;
    return c.u;
}
#else
__device__ __forceinline__ ushort f2bf_(float f){
    union{float f; uint u;} c; c.f = f;
    uint u = c.u + 0x7fffu + ((c.u >> 16) & 1u);
    return (ushort)(u >> 16);
}
__device__ __forceinline__ uint pack2(float a, float b){
    return ((uint)f2bf_(b) << 16) | (uint)f2bf_(a);
}
#endif
__device__ __forceinline__ ushort f2bf(float f){ return (ushort)(pack2(f, f) & 0xffffu); }

__device__ __forceinline__ float sigm(float x){ return 1.f/(1.f + __expf(-x)); }
__device__ __forceinline__ float tanhx(float x){
    float t = __expf(-2.f*fabsf(x));
    float r = (1.f - t)/(1.f + t);
    return x >= 0.f ? r : -r;
}
__device__ __forceinline__ float lo16u(uint u){ union{uint i; float f;} c; c.i = u << 16; return c.f; }
__device__ __forceinline__ float hi16u(uint u){ union{uint i; float f;} c; c.i = u & 0xffff0000u; return c.f; }

// ============ fused emb + Gi + WoE, all MFMA. 128 blocks x 512 threads, 16 rows each.
// Gi written bf16, P-permuted, [pos][b][g], with bih (+bhh for r,z gates) folded in.
__global__ __launch_bounds__(512) void k_embgi(
    const float* __restrict__ x,    const float* __restrict__ Wemb,
    const float* __restrict__ Wiha, const float* __restrict__ biha, const float* __restrict__ bhha,
    const float* __restrict__ Wihb, const float* __restrict__ bihb, const float* __restrict__ bhhb,
    const float* __restrict__ Wo,
    ushort* __restrict__ gia, ushort* __restrict__ gib, ushort* __restrict__ woE)
{
    __shared__ __align__(16) ushort LX[16*PAD];
    __shared__ __align__(16) ushort LW[128*PAD];
    __shared__ __align__(16) ushort LE[16*PAD];
    int tid = threadIdx.x;
    int lane = tid & 63, wave = tid >> 6;
    int quad = lane >> 4, n = lane & 15;
    int R0 = blockIdx.x * 16;
    int xr = tid >> 5, xc = (tid & 31) * 4;
    int wr_ = tid >> 2, wc = (tid & 3) * 32;

    f32x4 acc = {0.f,0.f,0.f,0.f};
    for (int kc = 0; kc < 8; ++kc){
        __syncthreads();
        {
            float4 v = *(const float4*)(x + (size_t)(R0 + xr)*DIN + kc*128 + xc);
            *(uint2*)&LX[xr*PAD + xc] = (uint2){pack2(v.x,v.y), pack2(v.z,v.w)};
            const float4* sw = (const float4*)(Wemb + (size_t)wr_*DIN + kc*128 + wc);
            float4 g0=sw[0],g1=sw[1],g2=sw[2],g3=sw[3],g4=sw[4],g5=sw[5],g6=sw[6],g7=sw[7];
            uint4* dB = (uint4*)&LW[wr_*PAD + wc];
            dB[0] = (uint4){pack2(g0.x,g0.y),pack2(g0.z,g0.w),pack2(g1.x,g1.y),pack2(g1.z,g1.w)};
            dB[1] = (uint4){pack2(g2.x,g2.y),pack2(g2.z,g2.w),pack2(g3.x,g3.y),pack2(g3.z,g3.w)};
            dB[2] = (uint4){pack2(g4.x,g4.y),pack2(g4.z,g4.w),pack2(g5.x,g5.y),pack2(g5.z,g5.w)};
            dB[3] = (uint4){pack2(g6.x,g6.y),pack2(g6.z,g6.w),pack2(g7.x,g7.y),pack2(g7.z,g7.w)};
        }
        __syncthreads();
#pragma unroll
        for (int kb = 0; kb < 4; ++kb){
            bf16x8 a = *(const bf16x8*)&LX[n*PAD + kb*32 + quad*8];
            bf16x8 b = *(const bf16x8*)&LW[(wave*16 + n)*PAD + kb*32 + quad*8];
            acc = __builtin_amdgcn_mfma_f32_16x16x32_bf16(a, b, acc, 0,0,0);
        }
    }
    {
        int e = wave*16 + n;
        float wo = Wo[e];
#pragma unroll
        for (int l = 0; l < 4; ++l){
            int m = quad*4 + l;
            LE[m*PAD + e] = f2bf(acc[l]);
            int row = R0 + m, b_ = row >> 7, pos = row & 127;
            woE[((size_t)(pos*Bn + b_))*HH + e] = f2bf(wo * acc[l]);
        }
    }
    for (int nc = 0; nc < 6; ++nc){
        const float* Wsrc = (nc < 3) ? Wiha : Wihb;
        int gband = (nc < 3) ? nc : nc - 3;
        __syncthreads();
        {
            const float4* sw = (const float4*)(Wsrc + (size_t)(gband*128 + wr_)*HH + wc);
            float4 g0=sw[0],g1=sw[1],g2=sw[2],g3=sw[3],g4=sw[4],g5=sw[5],g6=sw[6],g7=sw[7];
            uint4* dB = (uint4*)&LW[wr_*PAD + wc];
            dB[0] = (uint4){pack2(g0.x,g0.y),pack2(g0.z,g0.w),pack2(g1.x,g1.y),pack2(g1.z,g1.w)};
            dB[1] = (uint4){pack2(g2.x,g2.y),pack2(g2.z,g2.w),pack2(g3.x,g3.y),pack2(g3.z,g3.w)};
            dB[2] = (uint4){pack2(g4.x,g4.y),pack2(g4.z,g4.w),pack2(g5.x,g5.y),pack2(g5.z,g5.w)};
            dB[3] = (uint4){pack2(g6.x,g6.y),pack2(g6.z,g6.w),pack2(g7.x,g7.y),pack2(g7.z,g7.w)};
        }
        __syncthreads();
        f32x4 gc = {0.f,0.f,0.f,0.f};
#pragma unroll
        for (int kb = 0; kb < 4; ++kb){
            bf16x8 a = *(const bf16x8*)&LE[n*PAD + kb*32 + quad*8];
            bf16x8 b = *(const bf16x8*)&LW[(wave*16 + n)*PAD + kb*32 + quad*8];
            gc = __builtin_amdgcn_mfma_f32_16x16x32_bf16(a, b, gc, 0,0,0);
        }
        int g = gband*128 + wave*16 + n;
        const float* bi = (nc < 3) ? biha : bihb;
        const float* bh = (nc < 3) ? bhha : bhhb;
        float bias = bi[g] + ((gband < 2) ? bh[g] : 0.f);   // fold bhh for r,z only
        ushort* dst = (nc < 3) ? gia : gib;
        int P = (3*wave + gband)*16 + n;
#pragma unroll
        for (int l = 0; l < 4; ++l){
            int row = R0 + quad*4 + l, b_ = row >> 7, pos = row & 127;
            dst[((size_t)(pos*Bn + b_))*G3 + P] = f2bf(gc[l] + bias);
        }
    }
}

// ============ GRU recurrence body, compile-time GT (0=a emits s, 1=b emits q).
// 512 threads / 8 waves, 16 chains; one barrier per step; wave-local gate update;
// s/q buffered in LDS and flushed once (no global stores inside the step loop).
template<int GT>
__device__ __forceinline__ void gru_body(
    const float* __restrict__ Whh, const float* __restrict__ bhh,
    const float* __restrict__ Wsc, const float* __restrict__ bsc,
    const ushort* __restrict__ Gi, const ushort* __restrict__ WoE,
    float* __restrict__ outW, int i)
{
    constexpr int NT = GT ? 4 : 3;
    __shared__ __align__(16) ushort HF[2][2048];   // h in B-frag order, dbuf
    __shared__ float RED[2][128];                  // per-(wave,chain) partials, dbuf
    __shared__ __align__(16) float SQ[16][128];    // [chain][k] s or q
    int tid = threadIdx.x;
    int lane = tid & 63, u = tid >> 6;
    int quad = lane >> 4, n = lane & 15;
    int jb = u*16 + quad*4;

    // ---- static A-fragments (row-permuted weights), fully unrolled -> registers
    bf16x8 afr[NT][4];
#pragma unroll
    for (int g = 0; g < NT; ++g){
        const float* src = (g < 3) ? (Whh + (size_t)(g*HH + u*16 + n)*HH)
                                   : (Wsc + (size_t)(u*16 + n)*HH);
        float s = (GT && g == 3) ? 0.5f : 1.0f;    // fold 0.5 into Wb
#pragma unroll
        for (int kb = 0; kb < 4; ++kb){
            const float* p = src + kb*32 + quad*8;
            float4 a = *(const float4*)p, b2 = *(const float4*)(p+4);
            union { uint4 q; bf16x8 v; } cv;
            cv.q.x = pack2(s*a.x,  s*a.y);  cv.q.y = pack2(s*a.z,  s*a.w);
            cv.q.z = pack2(s*b2.x, s*b2.y); cv.q.w = pack2(s*b2.z, s*b2.w);
            afr[g][kb] = cv.v;
        }
    }
    float bh2[4], wsc4[4];
#pragma unroll
    for (int l = 0; l < 4; ++l){
        bh2[l]  = bhh[2*HH + jb + l];
        wsc4[l] = GT ? bsc[jb + l] : 0.5f*Wsc[jb + l];   // GT1: bb; GT0: 0.5*Wa
    }
    float bav = GT ? 0.f : bsc[0];
    float h4[4] = {0.f,0.f,0.f,0.f};
    if (tid < 256) ((uint4*)HF[1])[tid] = (uint4){0,0,0,0};

    const ushort* gp = Gi + ((size_t)(i*Bn + n))*G3 + u*48 + quad*4;
    uint2 pg0 = *(const uint2*)(gp);
    uint2 pg1 = *(const uint2*)(gp + 16);
    uint2 pg2 = *(const uint2*)(gp + 32);
    uint2 pwo = {0,0};
    __syncthreads();

    for (int k = 0; k <= i; ++k){
        int pos = i - k;
        // previous step's scalar -> LDS (pipelined; no global traffic)
        if (tid < 16){
            if (!GT && k > 0){
                const float* R = RED[(k+1)&1];
                SQ[tid][k-1] = R[tid]+R[16+tid]+R[32+tid]+R[48+tid]
                             + R[64+tid]+R[80+tid]+R[96+tid]+R[112+tid] + bav;
            }
            if (GT && k > 1){
                const float* R = RED[(k+1)&1];
                SQ[tid][k-2] = R[tid]+R[16+tid]+R[32+tid]+R[48+tid]
                             + R[64+tid]+R[80+tid]+R[96+tid]+R[112+tid];
            }
        }
        uint2 g0 = pg0, g1 = pg1, g2 = pg2, wo = pwo;
        int pnext = (pos > 0) ? pos - 1 : 0;
        const ushort* gp2 = Gi + ((size_t)(pnext*Bn + n))*G3 + u*48 + quad*4;
        pg0 = *(const uint2*)(gp2);
        pg1 = *(const uint2*)(gp2 + 16);
        pg2 = *(const uint2*)(gp2 + 32);
        if (GT) pwo = *(const uint2*)(WoE + (size_t)(pos*Bn + n)*HH + jb);

        const ushort* HR = HF[(k+1)&1];
        f32x4 acc[NT];
#pragma unroll
        for (int g = 0; g < NT; ++g) acc[g] = (f32x4){0.f,0.f,0.f,0.f};
#pragma unroll
        for (int kb = 0; kb < 4; ++kb){
            bf16x8 bfr = *(const bf16x8*)&HR[(64*kb + lane)*8];
#pragma unroll
            for (int g = 0; g < NT; ++g)
                acc[g] = __builtin_amdgcn_mfma_f32_16x16x32_bf16(afr[g][kb], bfr, acc[g], 0,0,0);
        }

        float part = 0.f;
        if (GT){   // q_{k-1}: 0.5*Wb h_{k-1} (in acc[3]) with WoE prefetched last step
            float wof[4] = {lo16u(wo.x), hi16u(wo.x), lo16u(wo.y), hi16u(wo.y)};
#pragma unroll
            for (int l = 0; l < 4; ++l)
                part = fmaf(wof[l], tanhx(acc[3][l] + wsc4[l]), part);
        }
        float gi0[4] = {lo16u(g0.x), hi16u(g0.x), lo16u(g0.y), hi16u(g0.y)};
        float gi1[4] = {lo16u(g1.x), hi16u(g1.x), lo16u(g1.y), hi16u(g1.y)};
        float gi2[4] = {lo16u(g2.x), hi16u(g2.x), lo16u(g2.y), hi16u(g2.y)};
#pragma unroll
        for (int l = 0; l < 4; ++l){
            float r = sigm(gi0[l] + acc[0][l]);                 // bhh_r folded in Gi
            float z = sigm(gi1[l] + acc[1][l]);                 // bhh_z folded in Gi
            float nn = tanhx(gi2[l] + r*(acc[2][l] + bh2[l]));
            h4[l] = (1.f - z)*nn + z*h4[l];
        }
        if (!GT) part = wsc4[0]*h4[0] + wsc4[1]*h4[1] + wsc4[2]*h4[2] + wsc4[3]*h4[3];

        {
            ushort* HW = HF[k&1];
            *(uint2*)&HW[((jb>>3)*16 + n)*8 + (jb&4)] =
                (uint2){pack2(h4[0],h4[1]), pack2(h4[2],h4[3])};
        }
        part += __shfl_xor(part, 16);
        part += __shfl_xor(part, 32);
        if (lane < 16) RED[k&1][u*16 + n] = part;
        __syncthreads();
    }

    // ---- tail
    if (tid < 16){
        const float* R = RED[i&1];
        float sum = R[tid]+R[16+tid]+R[32+tid]+R[48+tid]
                  + R[64+tid]+R[80+tid]+R[96+tid]+R[112+tid];
        if (!GT)        SQ[tid][i] = sum + bav;
        else if (i > 0) SQ[tid][i-1] = sum;
    }
    if (GT){   // q_i from final h (HF[i&1]) with WoE[pos=0] (in pwo)
        const ushort* HR = HF[i&1];
        f32x4 a3 = {0.f,0.f,0.f,0.f};
#pragma unroll
        for (int kb = 0; kb < 4; ++kb){
            bf16x8 bfr = *(const bf16x8*)&HR[(64*kb + lane)*8];
            a3 = __builtin_amdgcn_mfma_f32_16x16x32_bf16(afr[NT-1][kb], bfr, a3, 0,0,0);
        }
        float wof[4] = {lo16u(pwo.x), hi16u(pwo.x), lo16u(pwo.y), hi16u(pwo.y)};
        float part = 0.f;
#pragma unroll
        for (int l = 0; l < 4; ++l)
            part = fmaf(wof[l], tanhx(a3[l] + wsc4[l]), part);
        part += __shfl_xor(part, 16);
        part += __shfl_xor(part, 32);
        if (lane < 16) RED[(i+1)&1][u*16 + n] = part;
        __syncthreads();
        if (tid < 16){
            const float* R = RED[(i+1)&1];
            SQ[tid][i] = R[tid]+R[16+tid]+R[32+tid]+R[48+tid]
                       + R[64+tid]+R[80+tid]+R[96+tid]+R[112+tid];
        }
    }
    __syncthreads();
    {   // flush SQ -> global, coalesced float4 (k_out masks k > i)
        int cn = tid >> 5, k4 = (tid & 31) * 4;
        *(float4*)&outW[((size_t)(cn*Tn + i))*Tn + k4] = *(const float4*)&SQ[cn][k4];
    }
}

// grid = 256 linear; gt = blk & 1 so each XCD (id%8) hosts only one GRU type
// -> per-XCD L2 working set ~2 MB (bf16 Gi), everything L2-resident (R5: FETCH 8 MB).
__global__ __launch_bounds__(512, 2) void k_gru(
    const float* __restrict__ WhhA, const float* __restrict__ bhhA,
    const float* __restrict__ Wa,   const float* __restrict__ ba,
    const float* __restrict__ WhhB, const float* __restrict__ bhhB,
    const float* __restrict__ Wb,   const float* __restrict__ bb,
    const ushort* __restrict__ GiA, const ushort* __restrict__ GiB,
    const ushort* __restrict__ WoE,
    float* __restrict__ sW, float* __restrict__ qW)
{
    int i = Tn - 1 - (blockIdx.x >> 1);
    if ((blockIdx.x & 1) == 0) gru_body<0>(WhhA, bhhA, Wa, ba, GiA, nullptr, sW, i);
    else                       gru_body<1>(WhhB, bhhB, Wb, bb, GiB, WoE,    qW, i);
}

// ============ softmax(s) . q per row; one wave per (b,i)
__global__ __launch_bounds__(256) void k_out(const float* __restrict__ sW,
                                             const float* __restrict__ qW,
                                             const float* __restrict__ bo,
                                             float* __restrict__ out){
    int tid = threadIdx.x, lane = tid & 63, w = tid >> 6;
    int r = blockIdx.x*4 + w;
    int i = r & (Tn-1);
    const float* s = sW + (size_t)r*Tn;
    const float* q = qW + (size_t)r*Tn;
    float s0 = (lane     <= i) ? s[lane]      : -1e30f;
    float s1 = (64+lane  <= i) ? s[64+lane]   : -1e30f;
    float m = fmaxf(s0, s1);
#pragma unroll
    for (int off = 32; off; off >>= 1) m = fmaxf(m, __shfl_xor(m, off));
    float e0 = __expf(s0 - m), e1 = __expf(s1 - m);
    float q0 = (lane    <= i) ? q[lane]    : 0.f;
    float q1 = (64+lane <= i) ? q[64+lane] : 0.f;
    float num = e0*q0 + e1*q1, den = e0 + e1;
#pragma unroll
    for (int off = 32; off; off >>= 1){
        num += __shfl_xor(num, off);
        den += __shfl_xor(den, off);
    }
    if (lane == 0) out[r] = num/den + bo[0];
}

extern "C" void kernel_launch(void* const* d_in, const int* in_sizes, int n_in,
                              void* d_out, int out_size, void* d_ws, size_t ws_size,
                              hipStream_t stream) {
    const float* x     = (const float*)d_in[0];
    const float* Wemb  = (const float*)d_in[1];
    const float* Wih_a = (const float*)d_in[2];
    const float* Whh_a = (const float*)d_in[3];
    const float* bih_a = (const float*)d_in[4];
    const float* bhh_a = (const float*)d_in[5];
    const float* Wa    = (const float*)d_in[6];
    const float* ba    = (const float*)d_in[7];
    const float* Wih_b = (const float*)d_in[8];
    const float* Whh_b = (const float*)d_in[9];
    const float* bih_b = (const float*)d_in[10];
    const float* bhh_b = (const float*)d_in[11];
    const float* Wb    = (const float*)d_in[12];
    const float* bb    = (const float*)d_in[13];
    const float* Wo    = (const float*)d_in[14];
    const float* bo    = (const float*)d_in[15];

    const int NR = Bn*Tn;                            // 2048 rows
    ushort* giA = (ushort*)d_ws;                     // [pos][b][384] bf16, P-permuted
    ushort* giB = giA + (size_t)NR*G3;
    ushort* woE = giB + (size_t)NR*G3;               // [pos][b][128] bf16
    float*  sW  = (float*)(woE + (size_t)NR*HH);     // [b][i][k] fp32
    float*  qW  = sW + (size_t)NR*Tn;

    k_embgi<<<dim3(128), 512, 0, stream>>>(x, Wemb,
                                           Wih_a, bih_a, bhh_a,
                                           Wih_b, bih_b, bhh_b, Wo,
                                           giA, giB, woE);
    k_gru<<<dim3(256), 512, 0, stream>>>(Whh_a, bhh_a, Wa, ba,
                                         Whh_b, bhh_b, Wb, bb,
                                         giA, giB, woE, sW, qW);
    k_out<<<dim3(NR/4), 256, 0, stream>>>(sW, qW, bo, (float*)d_out);
}

// Round 8
// 317.082 us; speedup vs baseline: 2.0465x; 1.0824x over previous
//
#include <hip/hip_runtime.h>
#include <hip/hip_bf16.h>

typedef unsigned int uint;
typedef unsigned short ushort;
typedef __attribute__((ext_vector_type(8))) short bf16x8;
typedef __attribute__((ext_vector_type(4))) float f32x4;

#define Tn 128
#define Bn 16
#define HH 128
#define G3 384
#define DIN 1024
#define PAD 136   // ushort row stride (272 B, 16B-aligned, breaks pow2 banks)
#define SQP 132   // SQ row stride in floats (2-way bank alias = free)

#if __has_builtin(__builtin_amdgcn_cvt_pk_bf16_f32)
__device__ __forceinline__ uint pack2(float a, float b){
    auto v = __builtin_amdgcn_cvt_pk_bf16_f32(a, b);   // lo = a, hi = b, RNE
    union { decltype(v) v2; uint u; } c; c.v2 = v;
    return c.u;
}
#else
__device__ __forceinline__ ushort f2bf_(float f){
    union{float f; uint u;} c; c.f = f;
    uint u = c.u + 0x7fffu + ((c.u >> 16) & 1u);
    return (ushort)(u >> 16);
}
__device__ __forceinline__ uint pack2(float a, float b){
    return ((uint)f2bf_(b) << 16) | (uint)f2bf_(a);
}
#endif
__device__ __forceinline__ ushort f2bf(float f){ return (ushort)(pack2(f, f) & 0xffffu); }

__device__ __forceinline__ float sigm(float x){ return 1.f/(1.f + __expf(-x)); }
__device__ __forceinline__ float tanhx(float x){
    float t = __expf(-2.f*fabsf(x));
    float r = (1.f - t)/(1.f + t);
    return x >= 0.f ? r : -r;
}
__device__ __forceinline__ float lo16u(uint u){ union{uint i; float f;} c; c.i = u << 16; return c.f; }
__device__ __forceinline__ float hi16u(uint u){ union{uint i; float f;} c; c.i = u & 0xffff0000u; return c.f; }

// LDS-only barrier: cross-thread data flows only through LDS in the GRU loop,
// so we wait lgkmcnt(0) but deliberately leave global (vmcnt) prefetches in
// flight across the barrier (compiler __syncthreads would drain vmcnt(0)).
__device__ __forceinline__ void bar_lds(){
    asm volatile("s_waitcnt lgkmcnt(0)\n\ts_barrier" ::: "memory");
}

// ============ one-time fp32 -> bf16 weight conversion: Wemb | Wiha | Wihb
__global__ __launch_bounds__(256) void k_cvt(const float* __restrict__ wemb,
                                             const float* __restrict__ wiha,
                                             const float* __restrict__ wihb,
                                             ushort* __restrict__ dst){
    int idx = (blockIdx.x*256 + threadIdx.x)*8;
    const float* s; int off;
    if (idx < 131072){ s = wemb; off = idx; }
    else if (idx < 180224){ s = wiha; off = idx - 131072; }
    else { s = wihb; off = idx - 180224; }
    float4 f0 = *(const float4*)(s + off);
    float4 f1 = *(const float4*)(s + off + 4);
    *(uint4*)(dst + idx) = (uint4){pack2(f0.x,f0.y),pack2(f0.z,f0.w),
                                   pack2(f1.x,f1.y),pack2(f1.z,f1.w)};
}

// ============ fused emb + Gi + WoE, all MFMA. 128 blocks x 512 threads, 16 rows each.
// Weights pre-converted to bf16 -> staging is pure uint4 copy (no pack work).
__global__ __launch_bounds__(512) void k_embgi(
    const float* __restrict__ x,      const ushort* __restrict__ WembB,
    const ushort* __restrict__ WihaB, const ushort* __restrict__ WihbB,
    const float* __restrict__ biha,   const float* __restrict__ bhha,
    const float* __restrict__ bihb,   const float* __restrict__ bhhb,
    const float* __restrict__ Wo,
    ushort* __restrict__ gia, ushort* __restrict__ gib, ushort* __restrict__ woE)
{
    __shared__ __align__(16) ushort LX[16*PAD];
    __shared__ __align__(16) ushort LW[128*PAD];
    __shared__ __align__(16) ushort LE[16*PAD];
    int tid = threadIdx.x;
    int lane = tid & 63, wave = tid >> 6;
    int quad = lane >> 4, n = lane & 15;
    int R0 = blockIdx.x * 16;
    int xr = tid >> 5, xc = (tid & 31) * 4;
    int wr2 = tid >> 2, wc2 = (tid & 3) * 32;

    f32x4 acc = {0.f,0.f,0.f,0.f};
    for (int kc = 0; kc < 8; ++kc){
        __syncthreads();
        {
            float4 v = *(const float4*)(x + (size_t)(R0 + xr)*DIN + kc*128 + xc);
            *(uint2*)&LX[xr*PAD + xc] = (uint2){pack2(v.x,v.y), pack2(v.z,v.w)};
            const uint4* sw = (const uint4*)(WembB + (size_t)wr2*DIN + kc*128 + wc2);
            uint4* dB = (uint4*)&LW[wr2*PAD + wc2];
            dB[0]=sw[0]; dB[1]=sw[1]; dB[2]=sw[2]; dB[3]=sw[3];
        }
        __syncthreads();
#pragma unroll
        for (int kb = 0; kb < 4; ++kb){
            bf16x8 a = *(const bf16x8*)&LX[n*PAD + kb*32 + quad*8];
            bf16x8 b = *(const bf16x8*)&LW[(wave*16 + n)*PAD + kb*32 + quad*8];
            acc = __builtin_amdgcn_mfma_f32_16x16x32_bf16(a, b, acc, 0,0,0);
        }
    }
    {
        int e = wave*16 + n;
        float wo = Wo[e];
#pragma unroll
        for (int l = 0; l < 4; ++l){
            int m = quad*4 + l;
            LE[m*PAD + e] = f2bf(acc[l]);
            int row = R0 + m, b_ = row >> 7, pos = row & 127;
            woE[((size_t)(pos*Bn + b_))*HH + e] = f2bf(wo * acc[l]);
        }
    }
    for (int nc = 0; nc < 6; ++nc){
        const ushort* Wsrc = (nc < 3) ? WihaB : WihbB;
        int gband = (nc < 3) ? nc : nc - 3;
        __syncthreads();
        {
            const uint4* sw = (const uint4*)(Wsrc + (size_t)(gband*128 + wr2)*HH + wc2);
            uint4* dB = (uint4*)&LW[wr2*PAD + wc2];
            dB[0]=sw[0]; dB[1]=sw[1]; dB[2]=sw[2]; dB[3]=sw[3];
        }
        __syncthreads();
        f32x4 gc = {0.f,0.f,0.f,0.f};
#pragma unroll
        for (int kb = 0; kb < 4; ++kb){
            bf16x8 a = *(const bf16x8*)&LE[n*PAD + kb*32 + quad*8];
            bf16x8 b = *(const bf16x8*)&LW[(wave*16 + n)*PAD + kb*32 + quad*8];
            gc = __builtin_amdgcn_mfma_f32_16x16x32_bf16(a, b, gc, 0,0,0);
        }
        int g = gband*128 + wave*16 + n;
        const float* bi = (nc < 3) ? biha : bihb;
        const float* bh = (nc < 3) ? bhha : bhhb;
        float bias = bi[g] + ((gband < 2) ? bh[g] : 0.f);   // fold bhh for r,z only
        ushort* dst = (nc < 3) ? gia : gib;
        int P = (3*wave + gband)*16 + n;
#pragma unroll
        for (int l = 0; l < 4; ++l){
            int row = R0 + quad*4 + l, b_ = row >> 7, pos = row & 127;
            dst[((size_t)(pos*Bn + b_))*G3 + P] = f2bf(gc[l] + bias);
        }
    }
}

// ============ GRU recurrence body, compile-time GT (0=a emits s, 1=b emits q).
// s and q are produced by the MFMA itself (extra A-rows), no shuffles/reductions:
//  GT0: afr[3] row0 = 0.5*Wa -> s_k appears in C row 0 at step k+1.
//  GT1: wbeta = tanh(0.5*Wb*h+bb)*woe written to BF (B-frag layout); at step k+1
//       wave 0 MFMAs an all-ones A-row against BF -> column sums = q.
template<int GT>
__device__ __forceinline__ void gru_body(
    const float* __restrict__ Whh, const float* __restrict__ bhh,
    const float* __restrict__ Wsc, const float* __restrict__ bsc,
    const ushort* __restrict__ Gi, const ushort* __restrict__ WoE,
    float* __restrict__ outW, int i)
{
    __shared__ __align__(16) ushort HF[2][2048];   // h in B-frag order, dbuf
    __shared__ __align__(16) ushort BF[2][2048];   // wbeta in B-frag order, dbuf (GT1)
    __shared__ __align__(16) float SQ[16][SQP];    // [chain][k] s or q
    int tid = threadIdx.x;
    int lane = tid & 63, u = tid >> 6;
    int quad = lane >> 4, n = lane & 15;
    int jb = u*16 + quad*4;

    // ---- static A-fragments
    bf16x8 afr[4][4];
#pragma unroll
    for (int g = 0; g < 4; ++g){
        const float* src;
        float s;
        if (g < 3){ src = Whh + (size_t)(g*HH + u*16 + n)*HH; s = 1.f; }
        else if (GT){ src = Wsc + (size_t)(u*16 + n)*HH; s = 0.5f; }  // 0.5*Wb
        else { src = Wsc; s = 0.5f; }                                  // 0.5*Wa row
#pragma unroll
        for (int kb = 0; kb < 4; ++kb){
            const float* p = src + kb*32 + quad*8;
            float4 a = *(const float4*)p, b2 = *(const float4*)(p+4);
            union { uint4 q; bf16x8 v; } cv;
            cv.q.x = pack2(s*a.x,  s*a.y);  cv.q.y = pack2(s*a.z,  s*a.w);
            cv.q.z = pack2(s*b2.x, s*b2.y); cv.q.w = pack2(s*b2.z, s*b2.w);
            bf16x8 v = cv.v;
            if (GT == 0 && g == 3 && !(u == 0 && n == 0)){
                union { uint4 q; bf16x8 v; } z0; z0.q = (uint4){0,0,0,0};
                v = z0.v;   // only A-row 0 of wave 0 carries Wa
            }
            afr[g][kb] = v;
        }
    }
    bf16x8 onesf;   // A-row 0 = 1.0 (column-sum MFMA), GT1
    {
        union { uint4 q; bf16x8 v; } c1;
        uint o = (n == 0) ? 0x3F803F80u : 0u;
        c1.q = (uint4){o,o,o,o};
        onesf = c1.v;
    }
    float bh2[4], bb4[4];
#pragma unroll
    for (int l = 0; l < 4; ++l){
        bh2[l] = bhh[2*HH + jb + l];
        bb4[l] = GT ? bsc[jb + l] : 0.f;
    }
    float bav = GT ? 0.f : bsc[0];
    float h4[4] = {0.f,0.f,0.f,0.f};
    if (tid < 256) ((uint4*)HF[1])[tid] = (uint4){0,0,0,0};

    const ushort* gp = Gi + ((size_t)(i*Bn + n))*G3 + u*48 + quad*4;
    uint2 pg0 = *(const uint2*)(gp);
    uint2 pg1 = *(const uint2*)(gp + 16);
    uint2 pg2 = *(const uint2*)(gp + 32);
    uint2 pwo = {0,0};
    bar_lds();

    for (int k = 0; k <= i; ++k){
        int pos = i - k;
        uint2 g0 = pg0, g1 = pg1, g2 = pg2, wo = pwo;
        int pnext = (pos > 0) ? pos - 1 : 0;
        const ushort* gp2 = Gi + ((size_t)(pnext*Bn + n))*G3 + u*48 + quad*4;
        pg0 = *(const uint2*)(gp2);
        pg1 = *(const uint2*)(gp2 + 16);
        pg2 = *(const uint2*)(gp2 + 32);
        if (GT) pwo = *(const uint2*)(WoE + (size_t)(pos*Bn + n)*HH + jb);

        const ushort* HR = HF[(k+1)&1];
        f32x4 a0={0.f,0.f,0.f,0.f}, a1=a0, a2=a0, a3=a0;
#pragma unroll
        for (int kb = 0; kb < 4; ++kb){
            bf16x8 bfr = *(const bf16x8*)&HR[(64*kb + lane)*8];
            a3 = __builtin_amdgcn_mfma_f32_16x16x32_bf16(afr[3][kb], bfr, a3, 0,0,0);
            a0 = __builtin_amdgcn_mfma_f32_16x16x32_bf16(afr[0][kb], bfr, a0, 0,0,0);
            a2 = __builtin_amdgcn_mfma_f32_16x16x32_bf16(afr[2][kb], bfr, a2, 0,0,0);
            a1 = __builtin_amdgcn_mfma_f32_16x16x32_bf16(afr[1][kb], bfr, a1, 0,0,0);
        }
        if (GT && u == 0 && k >= 2){   // q_{k-2} = ones . BF (written step k-1)
            const ushort* BR = BF[(k+1)&1];
            f32x4 qa = {0.f,0.f,0.f,0.f};
#pragma unroll
            for (int kb = 0; kb < 4; ++kb){
                bf16x8 bq = *(const bf16x8*)&BR[(64*kb + lane)*8];
                qa = __builtin_amdgcn_mfma_f32_16x16x32_bf16(onesf, bq, qa, 0,0,0);
            }
            if (lane < 16) SQ[lane][k-2] = qa[0];
        }
        if (!GT && u == 0 && k >= 1 && lane < 16)
            SQ[lane][k-1] = a3[0] + bav;   // s_{k-1} from C row 0
        if (GT && k >= 1){   // wbeta_{k-1} -> BF[k&1]
            float wof[4] = {lo16u(wo.x), hi16u(wo.x), lo16u(wo.y), hi16u(wo.y)};
            float w0 = tanhx(a3[0]+bb4[0])*wof[0];
            float w1 = tanhx(a3[1]+bb4[1])*wof[1];
            float w2 = tanhx(a3[2]+bb4[2])*wof[2];
            float w3 = tanhx(a3[3]+bb4[3])*wof[3];
            *(uint2*)&BF[k&1][((jb>>3)*16 + n)*8 + (jb&4)] =
                (uint2){pack2(w0,w1), pack2(w2,w3)};
        }
        float gi0[4] = {lo16u(g0.x), hi16u(g0.x), lo16u(g0.y), hi16u(g0.y)};
        float gi1[4] = {lo16u(g1.x), hi16u(g1.x), lo16u(g1.y), hi16u(g1.y)};
        float gi2[4] = {lo16u(g2.x), hi16u(g2.x), lo16u(g2.y), hi16u(g2.y)};
#pragma unroll
        for (int l = 0; l < 4; ++l){
            float r = sigm(gi0[l] + a0[l]);                 // bhh_r folded in Gi
            float z = sigm(gi1[l] + a1[l]);                 // bhh_z folded in Gi
            float nn = tanhx(gi2[l] + r*(a2[l] + bh2[l]));
            h4[l] = nn + z*(h4[l] - nn);
        }
        *(uint2*)&HF[k&1][((jb>>3)*16 + n)*8 + (jb&4)] =
            (uint2){pack2(h4[0],h4[1]), pack2(h4[2],h4[3])};
        bar_lds();
    }

    // ---- tail: s_i / (wbeta_i -> q_{i-1}, q_i)
    if (!GT){
        if (u == 0){
            const ushort* HRf = HF[i&1];
            f32x4 a3 = {0.f,0.f,0.f,0.f};
#pragma unroll
            for (int kb = 0; kb < 4; ++kb){
                bf16x8 bfr = *(const bf16x8*)&HRf[(64*kb + lane)*8];
                a3 = __builtin_amdgcn_mfma_f32_16x16x32_bf16(afr[3][kb], bfr, a3, 0,0,0);
            }
            if (lane < 16) SQ[lane][i] = a3[0] + bav;
        }
        __syncthreads();
    } else {
        const ushort* HRf = HF[i&1];
        f32x4 a3 = {0.f,0.f,0.f,0.f};
#pragma unroll
        for (int kb = 0; kb < 4; ++kb){
            bf16x8 bfr = *(const bf16x8*)&HRf[(64*kb + lane)*8];
            a3 = __builtin_amdgcn_mfma_f32_16x16x32_bf16(afr[3][kb], bfr, a3, 0,0,0);
        }
        float wof[4] = {lo16u(pwo.x), hi16u(pwo.x), lo16u(pwo.y), hi16u(pwo.y)};
        float w0 = tanhx(a3[0]+bb4[0])*wof[0];
        float w1 = tanhx(a3[1]+bb4[1])*wof[1];
        float w2 = tanhx(a3[2]+bb4[2])*wof[2];
        float w3 = tanhx(a3[3]+bb4[3])*wof[3];
        *(uint2*)&BF[(i+1)&1][((jb>>3)*16 + n)*8 + (jb&4)] =
            (uint2){pack2(w0,w1), pack2(w2,w3)};
        __syncthreads();
        if (u == 0){
            if (i >= 1){
                const ushort* BR = BF[i&1];
                f32x4 qa = {0.f,0.f,0.f,0.f};
#pragma unroll
                for (int kb = 0; kb < 4; ++kb){
                    bf16x8 bq = *(const bf16x8*)&BR[(64*kb + lane)*8];
                    qa = __builtin_amdgcn_mfma_f32_16x16x32_bf16(onesf, bq, qa, 0,0,0);
                }
                if (lane < 16) SQ[lane][i-1] = qa[0];
            }
            {
                const ushort* BR = BF[(i+1)&1];
                f32x4 qa = {0.f,0.f,0.f,0.f};
#pragma unroll
                for (int kb = 0; kb < 4; ++kb){
                    bf16x8 bq = *(const bf16x8*)&BR[(64*kb + lane)*8];
                    qa = __builtin_amdgcn_mfma_f32_16x16x32_bf16(onesf, bq, qa, 0,0,0);
                }
                if (lane < 16) SQ[lane][i] = qa[0];
            }
        }
        __syncthreads();
    }
    {   // flush SQ -> global, coalesced float4 (k_out masks k > i)
        int cn = tid >> 5, k4 = (tid & 31) * 4;
        *(float4*)&outW[((size_t)(cn*Tn + i))*Tn + k4] = *(const float4*)&SQ[cn][k4];
    }
}

// grid = 256 linear; gt = blk & 1 so each XCD (id%8) hosts only one GRU type.
__global__ __launch_bounds__(512, 1) void k_gru(
    const float* __restrict__ WhhA, const float* __restrict__ bhhA,
    const float* __restrict__ Wa,   const float* __restrict__ ba,
    const float* __restrict__ WhhB, const float* __restrict__ bhhB,
    const float* __restrict__ Wb,   const float* __restrict__ bb,
    const ushort* __restrict__ GiA, const ushort* __restrict__ GiB,
    const ushort* __restrict__ WoE,
    float* __restrict__ sW, float* __restrict__ qW)
{
    int i = Tn - 1 - (blockIdx.x >> 1);
    if ((blockIdx.x & 1) == 0) gru_body<0>(WhhA, bhhA, Wa, ba, GiA, nullptr, sW, i);
    else                       gru_body<1>(WhhB, bhhB, Wb, bb, GiB, WoE,    qW, i);
}

// ============ softmax(s) . q per row; one wave per (b,i)
__global__ __launch_bounds__(256) void k_out(const float* __restrict__ sW,
                                             const float* __restrict__ qW,
                                             const float* __restrict__ bo,
                                             float* __restrict__ out){
    int tid = threadIdx.x, lane = tid & 63, w = tid >> 6;
    int r = blockIdx.x*4 + w;
    int i = r & (Tn-1);
    const float* s = sW + (size_t)r*Tn;
    const float* q = qW + (size_t)r*Tn;
    float s0 = (lane     <= i) ? s[lane]      : -1e30f;
    float s1 = (64+lane  <= i) ? s[64+lane]   : -1e30f;
    float m = fmaxf(s0, s1);
#pragma unroll
    for (int off = 32; off; off >>= 1) m = fmaxf(m, __shfl_xor(m, off));
    float e0 = __expf(s0 - m), e1 = __expf(s1 - m);
    float q0 = (lane    <= i) ? q[lane]    : 0.f;
    float q1 = (64+lane <= i) ? q[64+lane] : 0.f;
    float num = e0*q0 + e1*q1, den = e0 + e1;
#pragma unroll
    for (int off = 32; off; off >>= 1){
        num += __shfl_xor(num, off);
        den += __shfl_xor(den, off);
    }
    if (lane == 0) out[r] = num/den + bo[0];
}

extern "C" void kernel_launch(void* const* d_in, const int* in_sizes, int n_in,
                              void* d_out, int out_size, void* d_ws, size_t ws_size,
                              hipStream_t stream) {
    const float* x     = (const float*)d_in[0];
    const float* Wemb  = (const float*)d_in[1];
    const float* Wih_a = (const float*)d_in[2];
    const float* Whh_a = (const float*)d_in[3];
    const float* bih_a = (const float*)d_in[4];
    const float* bhh_a = (const float*)d_in[5];
    const float* Wa    = (const float*)d_in[6];
    const float* ba    = (const float*)d_in[7];
    const float* Wih_b = (const float*)d_in[8];
    const float* Whh_b = (const float*)d_in[9];
    const float* bih_b = (const float*)d_in[10];
    const float* bhh_b = (const float*)d_in[11];
    const float* Wb    = (const float*)d_in[12];
    const float* bb    = (const float*)d_in[13];
    const float* Wo    = (const float*)d_in[14];
    const float* bo    = (const float*)d_in[15];

    const int NR = Bn*Tn;                            // 2048 rows
    ushort* giA = (ushort*)d_ws;                     // [pos][b][384] bf16, P-permuted
    ushort* giB = giA + (size_t)NR*G3;
    ushort* woE = giB + (size_t)NR*G3;               // [pos][b][128] bf16
    float*  sW  = (float*)(woE + (size_t)NR*HH);     // [b][i][k] fp32
    float*  qW  = sW + (size_t)NR*Tn;
    ushort* wcv = (ushort*)(qW + (size_t)NR*Tn);     // bf16: Wemb|Wiha|Wihb
    ushort* wembB = wcv;                             // 131072
    ushort* wihaB = wcv + 131072;                    // 49152
    ushort* wihbB = wcv + 180224;                    // 49152

    k_cvt<<<dim3(112), 256, 0, stream>>>(Wemb, Wih_a, Wih_b, wcv);
    k_embgi<<<dim3(128), 512, 0, stream>>>(x, wembB, wihaB, wihbB,
                                           bih_a, bhh_a, bih_b, bhh_b, Wo,
                                           giA, giB, woE);
    k_gru<<<dim3(256), 512, 0, stream>>>(Whh_a, bhh_a, Wa, ba,
                                         Whh_b, bhh_b, Wb, bb,
                                         giA, giB, woE, sW, qW);
    k_out<<<dim3(NR/4), 256, 0, stream>>>(sW, qW, bo, (float*)d_out);
}

// Round 9
// 294.185 us; speedup vs baseline: 2.2057x; 1.0778x over previous
//
#include <hip/hip_runtime.h>
#include <hip/hip_bf16.h>

typedef unsigned int uint;
typedef unsigned short ushort;
typedef __attribute__((ext_vector_type(8))) short bf16x8;
typedef __attribute__((ext_vector_type(4))) float f32x4;

#define Tn 128
#define Bn 16
#define HH 128
#define G3 384
#define DIN 1024
#define PAD 136   // ushort row stride (272 B, 16B-aligned, breaks pow2 banks)
#define SQP 132   // SQ row stride in floats

#if __has_builtin(__builtin_amdgcn_cvt_pk_bf16_f32)
__device__ __forceinline__ uint pack2(float a, float b){
    auto v = __builtin_amdgcn_cvt_pk_bf16_f32(a, b);   // lo = a, hi = b, RNE
    union { decltype(v) v2; uint u; } c; c.v2 = v;
    return c.u;
}
#else
__device__ __forceinline__ ushort f2bf_(float f){
    union{float f; uint u;} c; c.f = f;
    uint u = c.u + 0x7fffu + ((c.u >> 16) & 1u);
    return (ushort)(u >> 16);
}
__device__ __forceinline__ uint pack2(float a, float b){
    return ((uint)f2bf_(b) << 16) | (uint)f2bf_(a);
}
#endif
__device__ __forceinline__ ushort f2bf(float f){ return (ushort)(pack2(f, f) & 0xffffu); }

__device__ __forceinline__ float sigm(float x){ return 1.f/(1.f + __expf(-x)); }
__device__ __forceinline__ float tanhx(float x){
    float t = __expf(-2.f*fabsf(x));
    float r = (1.f - t)/(1.f + t);
    return x >= 0.f ? r : -r;
}

// LDS-only barrier: leaves global prefetches (vmcnt) in flight.
__device__ __forceinline__ void bar_lds(){
    asm volatile("s_waitcnt lgkmcnt(0)\n\ts_barrier" ::: "memory");
}

// ============ one-time fp32 -> bf16 weight conversion: Wemb | Wiha | Wihb
__global__ __launch_bounds__(256) void k_cvt(const float* __restrict__ wemb,
                                             const float* __restrict__ wiha,
                                             const float* __restrict__ wihb,
                                             ushort* __restrict__ dst){
    int idx = (blockIdx.x*256 + threadIdx.x)*8;
    const float* s; int off;
    if (idx < 131072){ s = wemb; off = idx; }
    else if (idx < 180224){ s = wiha; off = idx - 131072; }
    else { s = wihb; off = idx - 180224; }
    float4 f0 = *(const float4*)(s + off);
    float4 f1 = *(const float4*)(s + off + 4);
    *(uint4*)(dst + idx) = (uint4){pack2(f0.x,f0.y),pack2(f0.z,f0.w),
                                   pack2(f1.x,f1.y),pack2(f1.z,f1.w)};
}

// ============ fused emb + Gi + WoE, all MFMA. 128 blocks x 512 threads, 16 rows each.
// Gi written FP32, P-permuted (tile 3u+gamma), bih(+bhh for r,z) folded in. WoE fp32.
__global__ __launch_bounds__(512) void k_embgi(
    const float* __restrict__ x,      const ushort* __restrict__ WembB,
    const ushort* __restrict__ WihaB, const ushort* __restrict__ WihbB,
    const float* __restrict__ biha,   const float* __restrict__ bhha,
    const float* __restrict__ bihb,   const float* __restrict__ bhhb,
    const float* __restrict__ Wo,
    float* __restrict__ gia, float* __restrict__ gib, float* __restrict__ woE)
{
    __shared__ __align__(16) ushort LX[16*PAD];
    __shared__ __align__(16) ushort LW[128*PAD];
    __shared__ __align__(16) ushort LE[16*PAD];
    int tid = threadIdx.x;
    int lane = tid & 63, wave = tid >> 6;
    int quad = lane >> 4, n = lane & 15;
    int R0 = blockIdx.x * 16;
    int xr = tid >> 5, xc = (tid & 31) * 4;
    int wr2 = tid >> 2, wc2 = (tid & 3) * 32;

    f32x4 acc = {0.f,0.f,0.f,0.f};
    for (int kc = 0; kc < 8; ++kc){
        __syncthreads();
        {
            float4 v = *(const float4*)(x + (size_t)(R0 + xr)*DIN + kc*128 + xc);
            *(uint2*)&LX[xr*PAD + xc] = (uint2){pack2(v.x,v.y), pack2(v.z,v.w)};
            const uint4* sw = (const uint4*)(WembB + (size_t)wr2*DIN + kc*128 + wc2);
            uint4* dB = (uint4*)&LW[wr2*PAD + wc2];
            dB[0]=sw[0]; dB[1]=sw[1]; dB[2]=sw[2]; dB[3]=sw[3];
        }
        __syncthreads();
#pragma unroll
        for (int kb = 0; kb < 4; ++kb){
            bf16x8 a = *(const bf16x8*)&LX[n*PAD + kb*32 + quad*8];
            bf16x8 b = *(const bf16x8*)&LW[(wave*16 + n)*PAD + kb*32 + quad*8];
            acc = __builtin_amdgcn_mfma_f32_16x16x32_bf16(a, b, acc, 0,0,0);
        }
    }
    {
        int e = wave*16 + n;
        float wo = Wo[e];
#pragma unroll
        for (int l = 0; l < 4; ++l){
            int m = quad*4 + l;
            LE[m*PAD + e] = f2bf(acc[l]);
            int row = R0 + m, b_ = row >> 7, pos = row & 127;
            woE[((size_t)(pos*Bn + b_))*HH + e] = wo * acc[l];
        }
    }
    for (int nc = 0; nc < 6; ++nc){
        const ushort* Wsrc = (nc < 3) ? WihaB : WihbB;
        int gband = (nc < 3) ? nc : nc - 3;
        __syncthreads();
        {
            const uint4* sw = (const uint4*)(Wsrc + (size_t)(gband*128 + wr2)*HH + wc2);
            uint4* dB = (uint4*)&LW[wr2*PAD + wc2];
            dB[0]=sw[0]; dB[1]=sw[1]; dB[2]=sw[2]; dB[3]=sw[3];
        }
        __syncthreads();
        f32x4 gc = {0.f,0.f,0.f,0.f};
#pragma unroll
        for (int kb = 0; kb < 4; ++kb){
            bf16x8 a = *(const bf16x8*)&LE[n*PAD + kb*32 + quad*8];
            bf16x8 b = *(const bf16x8*)&LW[(wave*16 + n)*PAD + kb*32 + quad*8];
            gc = __builtin_amdgcn_mfma_f32_16x16x32_bf16(a, b, gc, 0,0,0);
        }
        int g = gband*128 + wave*16 + n;
        const float* bi = (nc < 3) ? biha : bihb;
        const float* bh = (nc < 3) ? bhha : bhhb;
        float bias = bi[g] + ((gband < 2) ? bh[g] : 0.f);
        float* dst = (nc < 3) ? gia : gib;
        int P = (3*wave + gband)*16 + n;
#pragma unroll
        for (int l = 0; l < 4; ++l){
            int row = R0 + quad*4 + l, b_ = row >> 7, pos = row & 127;
            dst[((size_t)(pos*Bn + b_))*G3 + P] = gc[l] + bias;
        }
    }
}

// ============ GRU recurrence, 1024 threads, heterogeneous wave roles.
// Waves 0-7 (G): 3 Gh tiles each + gate update for dims [16u,16u+16).
// Waves 8-15 (P): GT1: Pb tile (0.5*Wb band) + wbeta -> BF; wave 8 also q-MFMA.
//                 GT0: wave 8 computes s via 0.5*Wa row; waves 9-15 idle (barriers only).
template<int GT>
__device__ __forceinline__ void gru_body(
    const float* __restrict__ Whh, const float* __restrict__ bhh,
    const float* __restrict__ Wsc, const float* __restrict__ bsc,
    const float* __restrict__ Gi,  const float* __restrict__ WoE,
    float* __restrict__ outW, int i)
{
    __shared__ __align__(16) ushort HF[2][2048];   // h in B-frag order, dbuf
    __shared__ __align__(16) ushort BFm[2][2048];  // wbeta in B-frag order, dbuf (GT1)
    __shared__ __align__(16) float SQ[16][SQP];    // [chain][k] s or q
    int tid = threadIdx.x;
    int lane = tid & 63, wave = tid >> 6;
    int quad = lane >> 4, n = lane & 15;

    if (tid < 256) ((uint4*)HF[1])[tid] = (uint4){0,0,0,0};

    if (wave < 8){
        // ================= G-waves: gates only =================
        int u = wave, jb = u*16 + quad*4;
        bf16x8 afr[3][4];
#pragma unroll
        for (int g = 0; g < 3; ++g){
            const float* src = Whh + (size_t)(g*HH + u*16 + n)*HH;
#pragma unroll
            for (int kb = 0; kb < 4; ++kb){
                const float* p = src + kb*32 + quad*8;
                float4 a = *(const float4*)p, b2 = *(const float4*)(p+4);
                union { uint4 q; bf16x8 v; } cv;
                cv.q.x = pack2(a.x,a.y);   cv.q.y = pack2(a.z,a.w);
                cv.q.z = pack2(b2.x,b2.y); cv.q.w = pack2(b2.z,b2.w);
                afr[g][kb] = cv.v;
            }
        }
        float bh2[4];
#pragma unroll
        for (int l = 0; l < 4; ++l) bh2[l] = bhh[2*HH + jb + l];
        float h4[4] = {0.f,0.f,0.f,0.f};

        const float* gp = Gi + ((size_t)(i*Bn + n))*G3 + u*48 + quad*4;
        float4 pg0 = *(const float4*)(gp);
        float4 pg1 = *(const float4*)(gp + 16);
        float4 pg2 = *(const float4*)(gp + 32);
        bar_lds();

        for (int k = 0; k <= i; ++k){
            int pos = i - k;
            float4 g0 = pg0, g1 = pg1, g2 = pg2;
            int pnext = (pos > 0) ? pos - 1 : 0;
            const float* gp2 = Gi + ((size_t)(pnext*Bn + n))*G3 + u*48 + quad*4;
            pg0 = *(const float4*)(gp2);
            pg1 = *(const float4*)(gp2 + 16);
            pg2 = *(const float4*)(gp2 + 32);

            const ushort* HR = HF[(k+1)&1];
            f32x4 a0={0.f,0.f,0.f,0.f}, a1=a0, a2=a0;
#pragma unroll
            for (int kb = 0; kb < 4; ++kb){
                bf16x8 bfr = *(const bf16x8*)&HR[(64*kb + lane)*8];
                a0 = __builtin_amdgcn_mfma_f32_16x16x32_bf16(afr[0][kb], bfr, a0, 0,0,0);
                a1 = __builtin_amdgcn_mfma_f32_16x16x32_bf16(afr[1][kb], bfr, a1, 0,0,0);
                a2 = __builtin_amdgcn_mfma_f32_16x16x32_bf16(afr[2][kb], bfr, a2, 0,0,0);
            }
            float gi0[4]={g0.x,g0.y,g0.z,g0.w};
            float gi1[4]={g1.x,g1.y,g1.z,g1.w};
            float gi2[4]={g2.x,g2.y,g2.z,g2.w};
#pragma unroll
            for (int l = 0; l < 4; ++l){
                float r  = sigm(gi0[l] + a0[l]);               // bhh_r folded in Gi
                float z  = sigm(gi1[l] + a1[l]);               // bhh_z folded in Gi
                float nn = tanhx(gi2[l] + r*(a2[l] + bh2[l]));
                h4[l] = nn + z*(h4[l] - nn);
            }
            *(uint2*)&HF[k&1][((jb>>3)*16 + n)*8 + (jb&4)] =
                (uint2){pack2(h4[0],h4[1]), pack2(h4[2],h4[3])};
            bar_lds();
        }
        if (GT){ bar_lds(); bar_lds(); } else { bar_lds(); }
    } else {
        // ================= P-waves =================
        int u2 = wave - 8, jb = u2*16 + quad*4;
        if (GT){
            bf16x8 afr3[4];
#pragma unroll
            for (int kb = 0; kb < 4; ++kb){
                const float* p = Wsc + (size_t)(u2*16 + n)*HH + kb*32 + quad*8;
                float4 a = *(const float4*)p, b2 = *(const float4*)(p+4);
                union { uint4 q; bf16x8 v; } cv;
                cv.q.x = pack2(0.5f*a.x, 0.5f*a.y);  cv.q.y = pack2(0.5f*a.z, 0.5f*a.w);
                cv.q.z = pack2(0.5f*b2.x,0.5f*b2.y); cv.q.w = pack2(0.5f*b2.z,0.5f*b2.w);
                afr3[kb] = cv.v;
            }
            bf16x8 onesf;
            {
                union { uint4 q; bf16x8 v; } c1;
                uint o = (n == 0) ? 0x3F803F80u : 0u;
                c1.q = (uint4){o,o,o,o};
                onesf = c1.v;
            }
            float bb4[4];
#pragma unroll
            for (int l = 0; l < 4; ++l) bb4[l] = bsc[jb + l];
            float4 pwo = *(const float4*)(WoE + ((size_t)(i*Bn + n))*HH + jb);
            bar_lds();

            for (int k = 0; k <= i; ++k){
                int pos = i - k;
                float4 wo = pwo;
                pwo = *(const float4*)(WoE + ((size_t)(pos*Bn + n))*HH + jb);

                const ushort* HR = HF[(k+1)&1];
                f32x4 a3 = {0.f,0.f,0.f,0.f};
#pragma unroll
                for (int kb = 0; kb < 4; ++kb){
                    bf16x8 bfr = *(const bf16x8*)&HR[(64*kb + lane)*8];
                    a3 = __builtin_amdgcn_mfma_f32_16x16x32_bf16(afr3[kb], bfr, a3, 0,0,0);
                }
                if (u2 == 0 && k >= 2){   // q_{k-2} = ones . BF (written step k-1)
                    const ushort* BR = BFm[(k+1)&1];
                    f32x4 qa = {0.f,0.f,0.f,0.f};
#pragma unroll
                    for (int kb = 0; kb < 4; ++kb){
                        bf16x8 bq = *(const bf16x8*)&BR[(64*kb + lane)*8];
                        qa = __builtin_amdgcn_mfma_f32_16x16x32_bf16(onesf, bq, qa, 0,0,0);
                    }
                    if (lane < 16) SQ[lane][k-2] = qa[0];
                }
                if (k >= 1){
                    float wof[4] = {wo.x, wo.y, wo.z, wo.w};
                    float w0 = tanhx(a3[0]+bb4[0])*wof[0];
                    float w1 = tanhx(a3[1]+bb4[1])*wof[1];
                    float w2 = tanhx(a3[2]+bb4[2])*wof[2];
                    float w3 = tanhx(a3[3]+bb4[3])*wof[3];
                    *(uint2*)&BFm[k&1][((jb>>3)*16 + n)*8 + (jb&4)] =
                        (uint2){pack2(w0,w1), pack2(w2,w3)};
                }
                bar_lds();
            }
            {   // tail: wbeta_i from h_i (HF[i&1]) with WoE[0] (in pwo)
                const ushort* HR = HF[i&1];
                f32x4 a3 = {0.f,0.f,0.f,0.f};
#pragma unroll
                for (int kb = 0; kb < 4; ++kb){
                    bf16x8 bfr = *(const bf16x8*)&HR[(64*kb + lane)*8];
                    a3 = __builtin_amdgcn_mfma_f32_16x16x32_bf16(afr3[kb], bfr, a3, 0,0,0);
                }
                float w0 = tanhx(a3[0]+bb4[0])*pwo.x;
                float w1 = tanhx(a3[1]+bb4[1])*pwo.y;
                float w2 = tanhx(a3[2]+bb4[2])*pwo.z;
                float w3 = tanhx(a3[3]+bb4[3])*pwo.w;
                *(uint2*)&BFm[(i+1)&1][((jb>>3)*16 + n)*8 + (jb&4)] =
                    (uint2){pack2(w0,w1), pack2(w2,w3)};
            }
            bar_lds();
            if (u2 == 0){
                if (i >= 1){
                    const ushort* BR = BFm[i&1];
                    f32x4 qa = {0.f,0.f,0.f,0.f};
#pragma unroll
                    for (int kb = 0; kb < 4; ++kb){
                        bf16x8 bq = *(const bf16x8*)&BR[(64*kb + lane)*8];
                        qa = __builtin_amdgcn_mfma_f32_16x16x32_bf16(onesf, bq, qa, 0,0,0);
                    }
                    if (lane < 16) SQ[lane][i-1] = qa[0];
                }
                {
                    const ushort* BR = BFm[(i+1)&1];
                    f32x4 qa = {0.f,0.f,0.f,0.f};
#pragma unroll
                    for (int kb = 0; kb < 4; ++kb){
                        bf16x8 bq = *(const bf16x8*)&BR[(64*kb + lane)*8];
                        qa = __builtin_amdgcn_mfma_f32_16x16x32_bf16(onesf, bq, qa, 0,0,0);
                    }
                    if (lane < 16) SQ[lane][i] = qa[0];
                }
            }
            bar_lds();
        } else {
            // GT0: wave 8 computes s_k = 0.5*Wa . h_k (A-row 0); waves 9-15 idle.
            if (u2 == 0){
                bf16x8 afr3[4];
#pragma unroll
                for (int kb = 0; kb < 4; ++kb){
                    const float* p = Wsc + kb*32 + quad*8;
                    float4 a = *(const float4*)p, b2 = *(const float4*)(p+4);
                    union { uint4 q; bf16x8 v; } cv;
                    if (n == 0){
                        cv.q.x = pack2(0.5f*a.x, 0.5f*a.y);  cv.q.y = pack2(0.5f*a.z, 0.5f*a.w);
                        cv.q.z = pack2(0.5f*b2.x,0.5f*b2.y); cv.q.w = pack2(0.5f*b2.z,0.5f*b2.w);
                    } else cv.q = (uint4){0,0,0,0};
                    afr3[kb] = cv.v;
                }
                float bav = bsc[0];
                bar_lds();
                for (int k = 0; k <= i; ++k){
                    if (k >= 1){   // s_{k-1} from h_{k-1} (HF[(k+1)&1])
                        const ushort* HR = HF[(k+1)&1];
                        f32x4 a3 = {0.f,0.f,0.f,0.f};
#pragma unroll
                        for (int kb = 0; kb < 4; ++kb){
                            bf16x8 bfr = *(const bf16x8*)&HR[(64*kb + lane)*8];
                            a3 = __builtin_amdgcn_mfma_f32_16x16x32_bf16(afr3[kb], bfr, a3, 0,0,0);
                        }
                        if (lane < 16) SQ[lane][k-1] = a3[0] + bav;
                    }
                    bar_lds();
                }
                {   // s_i from h_i
                    const ushort* HR = HF[i&1];
                    f32x4 a3 = {0.f,0.f,0.f,0.f};
#pragma unroll
                    for (int kb = 0; kb < 4; ++kb){
                        bf16x8 bfr = *(const bf16x8*)&HR[(64*kb + lane)*8];
                        a3 = __builtin_amdgcn_mfma_f32_16x16x32_bf16(afr3[kb], bfr, a3, 0,0,0);
                    }
                    if (lane < 16) SQ[lane][i] = a3[0] + bav;
                }
                bar_lds();
            } else {
                bar_lds();
                for (int k = 0; k <= i; ++k) bar_lds();
                bar_lds();
            }
        }
    }
    if (tid < 512){   // flush SQ -> global, coalesced float4 (k_out masks k > i)
        int cn = tid >> 5, k4 = (tid & 31) * 4;
        *(float4*)&outW[((size_t)(cn*Tn + i))*Tn + k4] = *(const float4*)&SQ[cn][k4];
    }
}

// grid = 256 linear; gt = blk & 1 so each XCD (id%8) hosts only one GRU type.
__global__ __launch_bounds__(1024, 1) void k_gru(
    const float* __restrict__ WhhA, const float* __restrict__ bhhA,
    const float* __restrict__ Wa,   const float* __restrict__ ba,
    const float* __restrict__ WhhB, const float* __restrict__ bhhB,
    const float* __restrict__ Wb,   const float* __restrict__ bb,
    const float* __restrict__ GiA,  const float* __restrict__ GiB,
    const float* __restrict__ WoE,
    float* __restrict__ sW, float* __restrict__ qW)
{
    int i = Tn - 1 - (blockIdx.x >> 1);
    if ((blockIdx.x & 1) == 0) gru_body<0>(WhhA, bhhA, Wa, ba, GiA, nullptr, sW, i);
    else                       gru_body<1>(WhhB, bhhB, Wb, bb, GiB, WoE,    qW, i);
}

// ============ softmax(s) . q per row; one wave per (b,i)
__global__ __launch_bounds__(256) void k_out(const float* __restrict__ sW,
                                             const float* __restrict__ qW,
                                             const float* __restrict__ bo,
                                             float* __restrict__ out){
    int tid = threadIdx.x, lane = tid & 63, w = tid >> 6;
    int r = blockIdx.x*4 + w;
    int i = r & (Tn-1);
    const float* s = sW + (size_t)r*Tn;
    const float* q = qW + (size_t)r*Tn;
    float s0 = (lane     <= i) ? s[lane]      : -1e30f;
    float s1 = (64+lane  <= i) ? s[64+lane]   : -1e30f;
    float m = fmaxf(s0, s1);
#pragma unroll
    for (int off = 32; off; off >>= 1) m = fmaxf(m, __shfl_xor(m, off));
    float e0 = __expf(s0 - m), e1 = __expf(s1 - m);
    float q0 = (lane    <= i) ? q[lane]    : 0.f;
    float q1 = (64+lane <= i) ? q[64+lane] : 0.f;
    float num = e0*q0 + e1*q1, den = e0 + e1;
#pragma unroll
    for (int off = 32; off; off >>= 1){
        num += __shfl_xor(num, off);
        den += __shfl_xor(den, off);
    }
    if (lane == 0) out[r] = num/den + bo[0];
}

extern "C" void kernel_launch(void* const* d_in, const int* in_sizes, int n_in,
                              void* d_out, int out_size, void* d_ws, size_t ws_size,
                              hipStream_t stream) {
    const float* x     = (const float*)d_in[0];
    const float* Wemb  = (const float*)d_in[1];
    const float* Wih_a = (const float*)d_in[2];
    const float* Whh_a = (const float*)d_in[3];
    const float* bih_a = (const float*)d_in[4];
    const float* bhh_a = (const float*)d_in[5];
    const float* Wa    = (const float*)d_in[6];
    const float* ba    = (const float*)d_in[7];
    const float* Wih_b = (const float*)d_in[8];
    const float* Whh_b = (const float*)d_in[9];
    const float* bih_b = (const float*)d_in[10];
    const float* bhh_b = (const float*)d_in[11];
    const float* Wb    = (const float*)d_in[12];
    const float* bb    = (const float*)d_in[13];
    const float* Wo    = (const float*)d_in[14];
    const float* bo    = (const float*)d_in[15];

    const int NR = Bn*Tn;                            // 2048 rows
    float* giA = (float*)d_ws;                       // [pos][b][384] fp32, P-permuted
    float* giB = giA + (size_t)NR*G3;
    float* woE = giB + (size_t)NR*G3;                // [pos][b][128] fp32
    float* sW  = woE + (size_t)NR*HH;                // [b][i][k] fp32
    float* qW  = sW + (size_t)NR*Tn;
    ushort* wcv = (ushort*)(qW + (size_t)NR*Tn);     // bf16: Wemb|Wiha|Wihb
    ushort* wembB = wcv;                             // 131072
    ushort* wihaB = wcv + 131072;                    // 49152
    ushort* wihbB = wcv + 180224;                    // 49152

    k_cvt<<<dim3(112), 256, 0, stream>>>(Wemb, Wih_a, Wih_b, wcv);
    k_embgi<<<dim3(128), 512, 0, stream>>>(x, wembB, wihaB, wihbB,
                                           bih_a, bhh_a, bih_b, bhh_b, Wo,
                                           giA, giB, woE);
    k_gru<<<dim3(256), 1024, 0, stream>>>(Whh_a, bhh_a, Wa, ba,
                                          Whh_b, bhh_b, Wb, bb,
                                          giA, giB, woE, sW, qW);
    k_out<<<dim3(NR/4), 256, 0, stream>>>(sW, qW, bo, (float*)d_out);
}

// Round 10
// 246.145 us; speedup vs baseline: 2.6362x; 1.1952x over previous
//
#include <hip/hip_runtime.h>
#include <hip/hip_bf16.h>

typedef unsigned int uint;
typedef unsigned short ushort;
typedef __attribute__((ext_vector_type(8))) short bf16x8;
typedef __attribute__((ext_vector_type(4))) float f32x4;

#define Tn 128
#define Bn 16
#define HH 128
#define G3 384
#define DIN 1024
#define PAD 136   // ushort row stride (272 B, 16B-aligned, breaks pow2 banks)
#define SQP 132   // SQ row stride in floats

#if __has_builtin(__builtin_amdgcn_cvt_pk_bf16_f32)
__device__ __forceinline__ uint pack2(float a, float b){
    auto v = __builtin_amdgcn_cvt_pk_bf16_f32(a, b);   // lo = a, hi = b, RNE
    union { decltype(v) v2; uint u; } c; c.v2 = v;
    return c.u;
}
#else
__device__ __forceinline__ ushort f2bf_(float f){
    union{float f; uint u;} c; c.f = f;
    uint u = c.u + 0x7fffu + ((c.u >> 16) & 1u);
    return (ushort)(u >> 16);
}
__device__ __forceinline__ uint pack2(float a, float b){
    return ((uint)f2bf_(b) << 16) | (uint)f2bf_(a);
}
#endif
__device__ __forceinline__ ushort f2bf(float f){ return (ushort)(pack2(f, f) & 0xffffu); }

// exp-based versions (used only in k_out epilogue)
__device__ __forceinline__ float sigm(float x){ return 1.f/(1.f + __expf(-x)); }

// ---- rational activations (no exp; 1 rcp each). Padé(7,6) for tanh,
// max abs err ~1e-4 with clamp at |x|=5 — far below bf16 noise.
__device__ __forceinline__ float rcpf(float x){ return __builtin_amdgcn_rcpf(x); }
__device__ __forceinline__ float tanh_rat(float x){
    x = fminf(5.f, fmaxf(-5.f, x));
    float t = x*x;
    float n = x*fmaf(t, fmaf(t, (t + 378.f), 17325.f), 135135.f);
    float d = fmaf(t, fmaf(t, fmaf(t, 28.f, 3150.f), 62370.f), 135135.f);
    return n * rcpf(d);
}
// sigmoid numerator with 0.5 folded: sigm(x) = 0.5 + nhalf(m)/den(m), m = x/2 clamped
__device__ __forceinline__ float sig_num(float m, float t){
    return m*fmaf(t, fmaf(t, fmaf(t, 0.5f, 189.f), 8662.5f), 67567.5f);
}
__device__ __forceinline__ float sig_den(float t){
    return fmaf(t, fmaf(t, fmaf(t, 28.f, 3150.f), 62370.f), 135135.f);
}

// LDS-only barrier: leaves global prefetches (vmcnt) in flight.
__device__ __forceinline__ void bar_lds(){
    asm volatile("s_waitcnt lgkmcnt(0)\n\ts_barrier" ::: "memory");
}

// ============ one-time fp32 -> bf16 weight conversion: Wemb | Wiha | Wihb
__global__ __launch_bounds__(256) void k_cvt(const float* __restrict__ wemb,
                                             const float* __restrict__ wiha,
                                             const float* __restrict__ wihb,
                                             ushort* __restrict__ dst){
    int idx = (blockIdx.x*256 + threadIdx.x)*8;
    const float* s; int off;
    if (idx < 131072){ s = wemb; off = idx; }
    else if (idx < 180224){ s = wiha; off = idx - 131072; }
    else { s = wihb; off = idx - 180224; }
    float4 f0 = *(const float4*)(s + off);
    float4 f1 = *(const float4*)(s + off + 4);
    *(uint4*)(dst + idx) = (uint4){pack2(f0.x,f0.y),pack2(f0.z,f0.w),
                                   pack2(f1.x,f1.y),pack2(f1.z,f1.w)};
}

// ============ fused emb + Gi + WoE, all MFMA. 128 blocks x 512 threads, 16 rows each.
// Gi written FP32, P-permuted (tile 3u+gamma), bih(+bhh for r,z) folded in. WoE fp32.
__global__ __launch_bounds__(512) void k_embgi(
    const float* __restrict__ x,      const ushort* __restrict__ WembB,
    const ushort* __restrict__ WihaB, const ushort* __restrict__ WihbB,
    const float* __restrict__ biha,   const float* __restrict__ bhha,
    const float* __restrict__ bihb,   const float* __restrict__ bhhb,
    const float* __restrict__ Wo,
    float* __restrict__ gia, float* __restrict__ gib, float* __restrict__ woE)
{
    __shared__ __align__(16) ushort LX[16*PAD];
    __shared__ __align__(16) ushort LW[128*PAD];
    __shared__ __align__(16) ushort LE[16*PAD];
    int tid = threadIdx.x;
    int lane = tid & 63, wave = tid >> 6;
    int quad = lane >> 4, n = lane & 15;
    int R0 = blockIdx.x * 16;
    int xr = tid >> 5, xc = (tid & 31) * 4;
    int wr2 = tid >> 2, wc2 = (tid & 3) * 32;

    f32x4 acc = {0.f,0.f,0.f,0.f};
    for (int kc = 0; kc < 8; ++kc){
        __syncthreads();
        {
            float4 v = *(const float4*)(x + (size_t)(R0 + xr)*DIN + kc*128 + xc);
            *(uint2*)&LX[xr*PAD + xc] = (uint2){pack2(v.x,v.y), pack2(v.z,v.w)};
            const uint4* sw = (const uint4*)(WembB + (size_t)wr2*DIN + kc*128 + wc2);
            uint4* dB = (uint4*)&LW[wr2*PAD + wc2];
            dB[0]=sw[0]; dB[1]=sw[1]; dB[2]=sw[2]; dB[3]=sw[3];
        }
        __syncthreads();
#pragma unroll
        for (int kb = 0; kb < 4; ++kb){
            bf16x8 a = *(const bf16x8*)&LX[n*PAD + kb*32 + quad*8];
            bf16x8 b = *(const bf16x8*)&LW[(wave*16 + n)*PAD + kb*32 + quad*8];
            acc = __builtin_amdgcn_mfma_f32_16x16x32_bf16(a, b, acc, 0,0,0);
        }
    }
    {
        int e = wave*16 + n;
        float wo = Wo[e];
#pragma unroll
        for (int l = 0; l < 4; ++l){
            int m = quad*4 + l;
            LE[m*PAD + e] = f2bf(acc[l]);
            int row = R0 + m, b_ = row >> 7, pos = row & 127;
            woE[((size_t)(pos*Bn + b_))*HH + e] = wo * acc[l];
        }
    }
    for (int nc = 0; nc < 6; ++nc){
        const ushort* Wsrc = (nc < 3) ? WihaB : WihbB;
        int gband = (nc < 3) ? nc : nc - 3;
        __syncthreads();
        {
            const uint4* sw = (const uint4*)(Wsrc + (size_t)(gband*128 + wr2)*HH + wc2);
            uint4* dB = (uint4*)&LW[wr2*PAD + wc2];
            dB[0]=sw[0]; dB[1]=sw[1]; dB[2]=sw[2]; dB[3]=sw[3];
        }
        __syncthreads();
        f32x4 gc = {0.f,0.f,0.f,0.f};
#pragma unroll
        for (int kb = 0; kb < 4; ++kb){
            bf16x8 a = *(const bf16x8*)&LE[n*PAD + kb*32 + quad*8];
            bf16x8 b = *(const bf16x8*)&LW[(wave*16 + n)*PAD + kb*32 + quad*8];
            gc = __builtin_amdgcn_mfma_f32_16x16x32_bf16(a, b, gc, 0,0,0);
        }
        int g = gband*128 + wave*16 + n;
        const float* bi = (nc < 3) ? biha : bihb;
        const float* bh = (nc < 3) ? bhha : bhhb;
        float bias = bi[g] + ((gband < 2) ? bh[g] : 0.f);
        float* dst = (nc < 3) ? gia : gib;
        int P = (3*wave + gband)*16 + n;
#pragma unroll
        for (int l = 0; l < 4; ++l){
            int row = R0 + quad*4 + l, b_ = row >> 7, pos = row & 127;
            dst[((size_t)(pos*Bn + b_))*G3 + P] = gc[l] + bias;
        }
    }
}

// ============ GRU recurrence, 1024 threads, heterogeneous wave roles.
// Waves 0-7 (G): 3 Gh tiles each + gate update for dims [16u,16u+16).
// Waves 8-15 (P): GT1: Pb tile (0.5*Wb band) + wbeta -> BF; wave 8 also q-MFMA.
//                 GT0: wave 8 computes s via 0.5*Wa row; waves 9-15 idle (barriers only).
// Activations are rational (no exp; shared rcp for r,z) — trans-pipe issue is the
// measured bottleneck (R9 post-mortem).
template<int GT>
__device__ __forceinline__ void gru_body(
    const float* __restrict__ Whh, const float* __restrict__ bhh,
    const float* __restrict__ Wsc, const float* __restrict__ bsc,
    const float* __restrict__ Gi,  const float* __restrict__ WoE,
    float* __restrict__ outW, int i)
{
    __shared__ __align__(16) ushort HF[2][2048];   // h in B-frag order, dbuf
    __shared__ __align__(16) ushort BFm[2][2048];  // wbeta in B-frag order, dbuf (GT1)
    __shared__ __align__(16) float SQ[16][SQP];    // [chain][k] s or q
    int tid = threadIdx.x;
    int lane = tid & 63, wave = tid >> 6;
    int quad = lane >> 4, n = lane & 15;

    if (tid < 256) ((uint4*)HF[1])[tid] = (uint4){0,0,0,0};

    if (wave < 8){
        // ================= G-waves: gates only =================
        int u = wave, jb = u*16 + quad*4;
        bf16x8 afr[3][4];
#pragma unroll
        for (int g = 0; g < 3; ++g){
            const float* src = Whh + (size_t)(g*HH + u*16 + n)*HH;
#pragma unroll
            for (int kb = 0; kb < 4; ++kb){
                const float* p = src + kb*32 + quad*8;
                float4 a = *(const float4*)p, b2 = *(const float4*)(p+4);
                union { uint4 q; bf16x8 v; } cv;
                cv.q.x = pack2(a.x,a.y);   cv.q.y = pack2(a.z,a.w);
                cv.q.z = pack2(b2.x,b2.y); cv.q.w = pack2(b2.z,b2.w);
                afr[g][kb] = cv.v;
            }
        }
        float bh2[4];
#pragma unroll
        for (int l = 0; l < 4; ++l) bh2[l] = bhh[2*HH + jb + l];
        float h4[4] = {0.f,0.f,0.f,0.f};

        const float* gp = Gi + ((size_t)(i*Bn + n))*G3 + u*48 + quad*4;
        float4 pg0 = *(const float4*)(gp);
        float4 pg1 = *(const float4*)(gp + 16);
        float4 pg2 = *(const float4*)(gp + 32);
        bar_lds();

        for (int k = 0; k <= i; ++k){
            int pos = i - k;
            float4 g0 = pg0, g1 = pg1, g2 = pg2;
            int pnext = (pos > 0) ? pos - 1 : 0;
            const float* gp2 = Gi + ((size_t)(pnext*Bn + n))*G3 + u*48 + quad*4;
            pg0 = *(const float4*)(gp2);
            pg1 = *(const float4*)(gp2 + 16);
            pg2 = *(const float4*)(gp2 + 32);

            const ushort* HR = HF[(k+1)&1];
            f32x4 a0={0.f,0.f,0.f,0.f}, a1=a0, a2=a0;
#pragma unroll
            for (int kb = 0; kb < 4; ++kb){
                bf16x8 bfr = *(const bf16x8*)&HR[(64*kb + lane)*8];
                a0 = __builtin_amdgcn_mfma_f32_16x16x32_bf16(afr[0][kb], bfr, a0, 0,0,0);
                a1 = __builtin_amdgcn_mfma_f32_16x16x32_bf16(afr[1][kb], bfr, a1, 0,0,0);
                a2 = __builtin_amdgcn_mfma_f32_16x16x32_bf16(afr[2][kb], bfr, a2, 0,0,0);
            }
            float gi0[4]={g0.x,g0.y,g0.z,g0.w};
            float gi1[4]={g1.x,g1.y,g1.z,g1.w};
            float gi2[4]={g2.x,g2.y,g2.z,g2.w};
#pragma unroll
            for (int l = 0; l < 4; ++l){
                // r,z sigmoids with one shared rcp
                float mr = fminf(5.f, fmaxf(-5.f, 0.5f*(gi0[l] + a0[l])));
                float mz = fminf(5.f, fmaxf(-5.f, 0.5f*(gi1[l] + a1[l])));
                float tr = mr*mr, tz = mz*mz;
                float nr = sig_num(mr, tr), nz = sig_num(mz, tz);
                float dr = sig_den(tr),     dz = sig_den(tz);
                float rD = rcpf(dr*dz);
                float r = fmaf(nr*dz, rD, 0.5f);
                float z = fmaf(nz*dr, rD, 0.5f);
                float nn = tanh_rat(gi2[l] + r*(a2[l] + bh2[l]));
                h4[l] = nn + z*(h4[l] - nn);
            }
            *(uint2*)&HF[k&1][((jb>>3)*16 + n)*8 + (jb&4)] =
                (uint2){pack2(h4[0],h4[1]), pack2(h4[2],h4[3])};
            bar_lds();
        }
        if (GT){ bar_lds(); bar_lds(); } else { bar_lds(); }
    } else {
        // ================= P-waves =================
        int u2 = wave - 8, jb = u2*16 + quad*4;
        if (GT){
            bf16x8 afr3[4];
#pragma unroll
            for (int kb = 0; kb < 4; ++kb){
                const float* p = Wsc + (size_t)(u2*16 + n)*HH + kb*32 + quad*8;
                float4 a = *(const float4*)p, b2 = *(const float4*)(p+4);
                union { uint4 q; bf16x8 v; } cv;
                cv.q.x = pack2(0.5f*a.x, 0.5f*a.y);  cv.q.y = pack2(0.5f*a.z, 0.5f*a.w);
                cv.q.z = pack2(0.5f*b2.x,0.5f*b2.y); cv.q.w = pack2(0.5f*b2.z,0.5f*b2.w);
                afr3[kb] = cv.v;
            }
            bf16x8 onesf;
            {
                union { uint4 q; bf16x8 v; } c1;
                uint o = (n == 0) ? 0x3F803F80u : 0u;
                c1.q = (uint4){o,o,o,o};
                onesf = c1.v;
            }
            float bb4[4];
#pragma unroll
            for (int l = 0; l < 4; ++l) bb4[l] = bsc[jb + l];
            float4 pwo = *(const float4*)(WoE + ((size_t)(i*Bn + n))*HH + jb);
            bar_lds();

            for (int k = 0; k <= i; ++k){
                int pos = i - k;
                float4 wo = pwo;
                pwo = *(const float4*)(WoE + ((size_t)(pos*Bn + n))*HH + jb);

                const ushort* HR = HF[(k+1)&1];
                f32x4 a3 = {0.f,0.f,0.f,0.f};
#pragma unroll
                for (int kb = 0; kb < 4; ++kb){
                    bf16x8 bfr = *(const bf16x8*)&HR[(64*kb + lane)*8];
                    a3 = __builtin_amdgcn_mfma_f32_16x16x32_bf16(afr3[kb], bfr, a3, 0,0,0);
                }
                if (u2 == 0 && k >= 2){   // q_{k-2} = ones . BF (written step k-1)
                    const ushort* BR = BFm[(k+1)&1];
                    f32x4 qa = {0.f,0.f,0.f,0.f};
#pragma unroll
                    for (int kb = 0; kb < 4; ++kb){
                        bf16x8 bq = *(const bf16x8*)&BR[(64*kb + lane)*8];
                        qa = __builtin_amdgcn_mfma_f32_16x16x32_bf16(onesf, bq, qa, 0,0,0);
                    }
                    if (lane < 16) SQ[lane][k-2] = qa[0];
                }
                if (k >= 1){
                    float w0 = tanh_rat(a3[0]+bb4[0])*wo.x;
                    float w1 = tanh_rat(a3[1]+bb4[1])*wo.y;
                    float w2 = tanh_rat(a3[2]+bb4[2])*wo.z;
                    float w3 = tanh_rat(a3[3]+bb4[3])*wo.w;
                    *(uint2*)&BFm[k&1][((jb>>3)*16 + n)*8 + (jb&4)] =
                        (uint2){pack2(w0,w1), pack2(w2,w3)};
                }
                bar_lds();
            }
            {   // tail: wbeta_i from h_i (HF[i&1]) with WoE[0] (in pwo)
                const ushort* HR = HF[i&1];
                f32x4 a3 = {0.f,0.f,0.f,0.f};
#pragma unroll
                for (int kb = 0; kb < 4; ++kb){
                    bf16x8 bfr = *(const bf16x8*)&HR[(64*kb + lane)*8];
                    a3 = __builtin_amdgcn_mfma_f32_16x16x32_bf16(afr3[kb], bfr, a3, 0,0,0);
                }
                float w0 = tanh_rat(a3[0]+bb4[0])*pwo.x;
                float w1 = tanh_rat(a3[1]+bb4[1])*pwo.y;
                float w2 = tanh_rat(a3[2]+bb4[2])*pwo.z;
                float w3 = tanh_rat(a3[3]+bb4[3])*pwo.w;
                *(uint2*)&BFm[(i+1)&1][((jb>>3)*16 + n)*8 + (jb&4)] =
                    (uint2){pack2(w0,w1), pack2(w2,w3)};
            }
            bar_lds();
            if (u2 == 0){
                if (i >= 1){
                    const ushort* BR = BFm[i&1];
                    f32x4 qa = {0.f,0.f,0.f,0.f};
#pragma unroll
                    for (int kb = 0; kb < 4; ++kb){
                        bf16x8 bq = *(const bf16x8*)&BR[(64*kb + lane)*8];
                        qa = __builtin_amdgcn_mfma_f32_16x16x32_bf16(onesf, bq, qa, 0,0,0);
                    }
                    if (lane < 16) SQ[lane][i-1] = qa[0];
                }
                {
                    const ushort* BR = BFm[(i+1)&1];
                    f32x4 qa = {0.f,0.f,0.f,0.f};
#pragma unroll
                    for (int kb = 0; kb < 4; ++kb){
                        bf16x8 bq = *(const bf16x8*)&BR[(64*kb + lane)*8];
                        qa = __builtin_amdgcn_mfma_f32_16x16x32_bf16(onesf, bq, qa, 0,0,0);
                    }
                    if (lane < 16) SQ[lane][i] = qa[0];
                }
            }
            bar_lds();
        } else {
            // GT0: wave 8 computes s_k = 0.5*Wa . h_k (A-row 0); waves 9-15 idle.
            if (u2 == 0){
                bf16x8 afr3[4];
#pragma unroll
                for (int kb = 0; kb < 4; ++kb){
                    const float* p = Wsc + kb*32 + quad*8;
                    float4 a = *(const float4*)p, b2 = *(const float4*)(p+4);
                    union { uint4 q; bf16x8 v; } cv;
                    if (n == 0){
                        cv.q.x = pack2(0.5f*a.x, 0.5f*a.y);  cv.q.y = pack2(0.5f*a.z, 0.5f*a.w);
                        cv.q.z = pack2(0.5f*b2.x,0.5f*b2.y); cv.q.w = pack2(0.5f*b2.z,0.5f*b2.w);
                    } else cv.q = (uint4){0,0,0,0};
                    afr3[kb] = cv.v;
                }
                float bav = bsc[0];
                bar_lds();
                for (int k = 0; k <= i; ++k){
                    if (k >= 1){   // s_{k-1} from h_{k-1} (HF[(k+1)&1])
                        const ushort* HR = HF[(k+1)&1];
                        f32x4 a3 = {0.f,0.f,0.f,0.f};
#pragma unroll
                        for (int kb = 0; kb < 4; ++kb){
                            bf16x8 bfr = *(const bf16x8*)&HR[(64*kb + lane)*8];
                            a3 = __builtin_amdgcn_mfma_f32_16x16x32_bf16(afr3[kb], bfr, a3, 0,0,0);
                        }
                        if (lane < 16) SQ[lane][k-1] = a3[0] + bav;
                    }
                    bar_lds();
                }
                {   // s_i from h_i
                    const ushort* HR = HF[i&1];
                    f32x4 a3 = {0.f,0.f,0.f,0.f};
#pragma unroll
                    for (int kb = 0; kb < 4; ++kb){
                        bf16x8 bfr = *(const bf16x8*)&HR[(64*kb + lane)*8];
                        a3 = __builtin_amdgcn_mfma_f32_16x16x32_bf16(afr3[kb], bfr, a3, 0,0,0);
                    }
                    if (lane < 16) SQ[lane][i] = a3[0] + bav;
                }
                bar_lds();
            } else {
                bar_lds();
                for (int k = 0; k <= i; ++k) bar_lds();
                bar_lds();
            }
        }
    }
    if (tid < 512){   // flush SQ -> global, coalesced float4 (k_out masks k > i)
        int cn = tid >> 5, k4 = (tid & 31) * 4;
        *(float4*)&outW[((size_t)(cn*Tn + i))*Tn + k4] = *(const float4*)&SQ[cn][k4];
    }
}

// grid = 256 linear; gt = blk & 1 so each XCD (id%8) hosts only one GRU type.
__global__ __launch_bounds__(1024, 1) void k_gru(
    const float* __restrict__ WhhA, const float* __restrict__ bhhA,
    const float* __restrict__ Wa,   const float* __restrict__ ba,
    const float* __restrict__ WhhB, const float* __restrict__ bhhB,
    const float* __restrict__ Wb,   const float* __restrict__ bb,
    const float* __restrict__ GiA,  const float* __restrict__ GiB,
    const float* __restrict__ WoE,
    float* __restrict__ sW, float* __restrict__ qW)
{
    int i = Tn - 1 - (blockIdx.x >> 1);
    if ((blockIdx.x & 1) == 0) gru_body<0>(WhhA, bhhA, Wa, ba, GiA, nullptr, sW, i);
    else                       gru_body<1>(WhhB, bhhB, Wb, bb, GiB, WoE,    qW, i);
}

// ============ softmax(s) . q per row; one wave per (b,i)
__global__ __launch_bounds__(256) void k_out(const float* __restrict__ sW,
                                             const float* __restrict__ qW,
                                             const float* __restrict__ bo,
                                             float* __restrict__ out){
    int tid = threadIdx.x, lane = tid & 63, w = tid >> 6;
    int r = blockIdx.x*4 + w;
    int i = r & (Tn-1);
    const float* s = sW + (size_t)r*Tn;
    const float* q = qW + (size_t)r*Tn;
    float s0 = (lane     <= i) ? s[lane]      : -1e30f;
    float s1 = (64+lane  <= i) ? s[64+lane]   : -1e30f;
    float m = fmaxf(s0, s1);
#pragma unroll
    for (int off = 32; off; off >>= 1) m = fmaxf(m, __shfl_xor(m, off));
    float e0 = __expf(s0 - m), e1 = __expf(s1 - m);
    float q0 = (lane    <= i) ? q[lane]    : 0.f;
    float q1 = (64+lane <= i) ? q[64+lane] : 0.f;
    float num = e0*q0 + e1*q1, den = e0 + e1;
#pragma unroll
    for (int off = 32; off; off >>= 1){
        num += __shfl_xor(num, off);
        den += __shfl_xor(den, off);
    }
    if (lane == 0) out[r] = num/den + bo[0];
}

extern "C" void kernel_launch(void* const* d_in, const int* in_sizes, int n_in,
                              void* d_out, int out_size, void* d_ws, size_t ws_size,
                              hipStream_t stream) {
    const float* x     = (const float*)d_in[0];
    const float* Wemb  = (const float*)d_in[1];
    const float* Wih_a = (const float*)d_in[2];
    const float* Whh_a = (const float*)d_in[3];
    const float* bih_a = (const float*)d_in[4];
    const float* bhh_a = (const float*)d_in[5];
    const float* Wa    = (const float*)d_in[6];
    const float* ba    = (const float*)d_in[7];
    const float* Wih_b = (const float*)d_in[8];
    const float* Whh_b = (const float*)d_in[9];
    const float* bih_b = (const float*)d_in[10];
    const float* bhh_b = (const float*)d_in[11];
    const float* Wb    = (const float*)d_in[12];
    const float* bb    = (const float*)d_in[13];
    const float* Wo    = (const float*)d_in[14];
    const float* bo    = (const float*)d_in[15];

    const int NR = Bn*Tn;                            // 2048 rows
    float* giA = (float*)d_ws;                       // [pos][b][384] fp32, P-permuted
    float* giB = giA + (size_t)NR*G3;
    float* woE = giB + (size_t)NR*G3;                // [pos][b][128] fp32
    float* sW  = woE + (size_t)NR*HH;                // [b][i][k] fp32
    float* qW  = sW + (size_t)NR*Tn;
    ushort* wcv = (ushort*)(qW + (size_t)NR*Tn);     // bf16: Wemb|Wiha|Wihb
    ushort* wembB = wcv;                             // 131072
    ushort* wihaB = wcv + 131072;                    // 49152
    ushort* wihbB = wcv + 180224;                    // 49152

    k_cvt<<<dim3(112), 256, 0, stream>>>(Wemb, Wih_a, Wih_b, wcv);
    k_embgi<<<dim3(128), 512, 0, stream>>>(x, wembB, wihaB, wihbB,
                                           bih_a, bhh_a, bih_b, bhh_b, Wo,
                                           giA, giB, woE);
    k_gru<<<dim3(256), 1024, 0, stream>>>(Whh_a, bhh_a, Wa, ba,
                                          Whh_b, bhh_b, Wb, bb,
                                          giA, giB, woE, sW, qW);
    k_out<<<dim3(NR/4), 256, 0, stream>>>(sW, qW, bo, (float*)d_out);
}